// Round 7
// baseline (442.358 us; speedup 1.0000x reference)
//
#include <hip/hip_runtime.h>
#include <hip/hip_bf16.h>

// ---------- types ----------
typedef unsigned short ushortT;
typedef __bf16 bf16x8 __attribute__((ext_vector_type(8)));
typedef float f32x4 __attribute__((ext_vector_type(4)));
typedef ushortT ush8 __attribute__((ext_vector_type(8)));
typedef ushortT ush4 __attribute__((ext_vector_type(4)));

#define MFMA16(a, b, c) __builtin_amdgcn_mfma_f32_16x16x32_bf16((a), (b), (c), 0, 0, 0)

__device__ __forceinline__ ushortT f2b(float f) {
  __hip_bfloat16 h = __float2bfloat16(f);
  return __builtin_bit_cast(ushortT, h);
}
__device__ __forceinline__ float b2f(ushortT u) {
  __hip_bfloat16 h = __builtin_bit_cast(__hip_bfloat16, u);
  return __bfloat162float(h);
}

// scale 8 bf16 by scalar s in f32, round back to bf16 (v_cvt_pk_bf16_f32)
__device__ __forceinline__ bf16x8 scale8(bf16x8 a, float s) {
  union { bf16x8 v; unsigned int u[4]; } in, out;
  in.v = a;
#pragma unroll
  for (int p = 0; p < 4; p++) {
    float lo = __builtin_bit_cast(float, in.u[p] << 16);
    float hi = __builtin_bit_cast(float, in.u[p] & 0xffff0000u);
    lo *= s;
    hi *= s;
    unsigned int r;
    asm("v_cvt_pk_bf16_f32 %0, %1, %2" : "=v"(r) : "v"(lo), "v"(hi));
    out.u[p] = r;
  }
  return out.v;
}

// pack 8 f32 -> 8 bf16 (16B) via v_cvt_pk_bf16_f32
__device__ __forceinline__ void packB16(const f32x4 lo, const f32x4 hi, void* dst) {
  unsigned int o0, o1, o2, o3;
  asm("v_cvt_pk_bf16_f32 %0, %1, %2" : "=v"(o0) : "v"(lo[0]), "v"(lo[1]));
  asm("v_cvt_pk_bf16_f32 %0, %1, %2" : "=v"(o1) : "v"(lo[2]), "v"(lo[3]));
  asm("v_cvt_pk_bf16_f32 %0, %1, %2" : "=v"(o2) : "v"(hi[0]), "v"(hi[1]));
  asm("v_cvt_pk_bf16_f32 %0, %1, %2" : "=v"(o3) : "v"(hi[2]), "v"(hi[3]));
  uint4 u; u.x = o0; u.y = o1; u.z = o2; u.w = o3;
  *(uint4*)dst = u;
}

// ---------- problem dims ----------
// B=4, S=512, D=256, ROWS = B*S = 2048
#define ACT_E 524288   // 2048*256 elements
#define WD_E  65536    // 256*256

// ---------- ws layout (bytes) ----------
// transients [0, ~27.4MB) are dead by bilinear time; PART f32 (67MB) overlaps.
#define OFF_ACT16   0u          // 3 * ACT_E * 2 = 3145728
#define OFF_ACTT16  3145728u    // 3 * ACT_E * 2
#define OFF_W16T    6291456u    // 9 * WD_E * 2 = 1179648
#define OFF_PROJ16  7471104u    // 5 * ACT_E * 2 = 5242880
#define OFF_P16     12713984u   // 4 * 1048576 * 2 = 8388608
#define OFF_VC16    21102592u   // ACT_E*2
#define OFF_AC16    22151168u
#define OFF_PVV32   23199744u   // ACT_E*4
#define OFF_PVA32   25296896u   // ends 27394048
#define OFF_PART    0u          // 32 * 2048*256*4 = 67108864 (overlaps transients)
#define OFF_CFV16   67108864u   // ACT_E*2
#define OFF_CFA16   68157440u   // ends 69206016

// =====================================================================
// 1) convert img/audio/common fp32 -> bf16 (same layout)
__global__ void k_cvt_acts(const float* __restrict__ img, const float* __restrict__ aud,
                           const float* __restrict__ com, ushortT* __restrict__ dst) {
  int i4 = blockIdx.x * 256 + threadIdx.x;
#pragma unroll
  for (int q = 0; q < 4; q++) {
    int idx4 = i4 + q * 98304;
    int flat = idx4 * 4;
    const float* src;
    int off;
    if (flat < 524288)        { src = img; off = flat; }
    else if (flat < 1048576)  { src = aud; off = flat - 524288; }
    else                      { src = com; off = flat - 1048576; }
    float4 v = *(const float4*)(src + off);
    ush4 u = { f2b(v.x), f2b(v.y), f2b(v.z), f2b(v.w) };
    *(ush4*)(dst + idx4 * 4) = u;
  }
}

// 2) transpose+convert
__global__ void k_transpose(const float* __restrict__ img, const float* __restrict__ aud,
                            const float* __restrict__ com,
                            const float* w0, const float* w1, const float* w2,
                            const float* w3, const float* w4, const float* w5,
                            const float* w6, const float* w7, const float* w8,
                            ushortT* __restrict__ actT, ushortT* __restrict__ wT) {
  __shared__ ushortT tl[64][72];
  int tid = threadIdx.x;
  int bx = blockIdx.x;
  const float* src;
  ushortT* dst;
  int R, C, r0, c0;
  if (bx < 384) {
    int inst = bx >> 5, tile = bx & 31;
    int act = inst >> 2, bb = inst & 3;
    src = (act == 0 ? img : (act == 1 ? aud : com)) + bb * 131072;
    dst = actT + act * 524288 + bb * 131072;
    R = 512; C = 256;
    r0 = (tile >> 2) * 64; c0 = (tile & 3) * 64;
  } else {
    int bw = bx - 384;
    int w = bw >> 4, tile = bw & 15;
    const float* s;
    switch (w) {
      case 0: s = w0; break; case 1: s = w1; break; case 2: s = w2; break;
      case 3: s = w3; break; case 4: s = w4; break; case 5: s = w5; break;
      case 6: s = w6; break; case 7: s = w7; break; default: s = w8; break;
    }
    src = s;
    dst = wT + w * 65536;
    R = 256; C = 256;
    r0 = (tile >> 2) * 64; c0 = (tile & 3) * 64;
  }
#pragma unroll
  for (int q = 0; q < 4; q++) {
    int rr = q * 16 + (tid >> 4);
    int cs = (tid & 15) * 4;
    float4 v = *(const float4*)(src + (r0 + rr) * C + c0 + cs);
    tl[rr][cs + 0] = f2b(v.x);
    tl[rr][cs + 1] = f2b(v.y);
    tl[rr][cs + 2] = f2b(v.z);
    tl[rr][cs + 3] = f2b(v.w);
  }
  __syncthreads();
#pragma unroll
  for (int q = 0; q < 4; q++) {
    int cc = q * 16 + (tid >> 4);
    int rs = (tid & 15) * 4;
    ush4 u = { tl[rs + 0][cc], tl[rs + 1][cc], tl[rs + 2][cc], tl[rs + 3][cc] };
    *(ush4*)(dst + (c0 + cc) * R + r0 + rs) = u;
  }
}

// =====================================================================
// 3) five input linears
__global__ __launch_bounds__(512) void k_linear5(
    const ushortT* __restrict__ act16, const ushortT* __restrict__ wT,
    const float* __restrict__ b0, const float* __restrict__ b1,
    const float* __restrict__ b2, const float* __restrict__ b3,
    const float* __restrict__ b4, ushortT* __restrict__ proj16) {
  __shared__ ushortT Al[4][32][8];
  __shared__ ushortT Bl[4][256][8];
  const int tid = threadIdx.x, l = tid & 63, w = tid >> 6;
  const int bx = blockIdx.x;
  const int op = bx >> 6, sblk = bx & 63;
  const int s0 = sblk * 32;
  const int xsel = (op == 4) ? 2 : (op & 1);
  const ushortT* X = act16 + xsel * ACT_E;
  const ushortT* W = wT + op * WD_E;
  const float* bias = op == 0 ? b0 : op == 1 ? b1 : op == 2 ? b2 : op == 3 ? b3 : b4;
  ushortT* out = proj16 + op * ACT_E;

  f32x4 acc[2][2] = {};
  ush8 ra, rb[2];
  int a_row = tid >> 2, a_seg = tid & 3;

  auto sload = [&](int k0) {
    if (tid < 128) ra = *(const ush8*)(X + (s0 + a_row) * 256 + k0 + a_seg * 8);
#pragma unroll
    for (int q = 0; q < 2; q++) {
      int slot = tid + q * 512;
      rb[q] = *(const ush8*)(W + (slot >> 2) * 256 + k0 + (slot & 3) * 8);
    }
  };
  auto swrite = [&]() {
    if (tid < 128) *(ush8*)(&Al[a_seg][a_row][0]) = ra;
#pragma unroll
    for (int q = 0; q < 2; q++) {
      int slot = tid + q * 512;
      *(ush8*)(&Bl[slot & 3][slot >> 2][0]) = rb[q];
    }
  };

  sload(0); swrite(); __syncthreads();
  for (int s = 0; s < 8; s++) {
    if (s < 7) sload((s + 1) * 32);
    int ks = l >> 4;
    bf16x8 a[2], bb[2];
#pragma unroll
    for (int m = 0; m < 2; m++) a[m] = *(const bf16x8*)(&Al[ks][m * 16 + (l & 15)][0]);
#pragma unroll
    for (int n = 0; n < 2; n++) bb[n] = *(const bf16x8*)(&Bl[ks][w * 32 + n * 16 + (l & 15)][0]);
#pragma unroll
    for (int m = 0; m < 2; m++)
#pragma unroll
      for (int n = 0; n < 2; n++) acc[m][n] = MFMA16(a[m], bb[n], acc[m][n]);
    if (s == 7) break;
    __syncthreads();
    swrite();
    __syncthreads();
  }
#pragma unroll
  for (int m = 0; m < 2; m++)
#pragma unroll
    for (int n = 0; n < 2; n++)
#pragma unroll
      for (int r = 0; r < 4; r++) {
        int row = s0 + m * 16 + (l >> 4) * 4 + r;
        int col = w * 32 + n * 16 + (l & 15);
        out[row * 256 + col] = f2b(acc[m][n][r] + bias[col]);
      }
}

// =====================================================================
// 4) attention: P = softmax(Q K^T) * (1/16)
__global__ __launch_bounds__(512) void k_attn(const ushortT* __restrict__ proj16,
                                              ushortT* __restrict__ P16) {
  __shared__ ushortT Ql[8][4][32][8];
  __shared__ ushortT Kl[4][512][8];
  __shared__ float red[32][8];
  const int tid = threadIdx.x, l = tid & 63, w = tid >> 6;
  const int bx = blockIdx.x;
  const int p = bx >> 6, b = (bx >> 4) & 3, sblk = bx & 15;
  const int s0 = sblk * 32;
  const int qsel = (p < 2) ? 0 : 1;
  const int ksel = (p == 0) ? 2 : (p == 2) ? 3 : 4;
  const ushortT* Q = proj16 + qsel * ACT_E + b * 131072;
  const ushortT* K = proj16 + ksel * ACT_E + b * 131072;
  ushortT* P = P16 + p * 1048576 + b * 262144;

#pragma unroll
  for (int q = 0; q < 2; q++) {
    int slot = tid + q * 512;
    int row = slot >> 5, seg = slot & 31;
    ush8 v = *(const ush8*)(Q + (s0 + row) * 256 + seg * 8);
    *(ush8*)(&Ql[seg >> 2][seg & 3][row][0]) = v;
  }

  f32x4 acc[2][4] = {};
  ush8 rk[4];
  auto kload = [&](int d0) {
#pragma unroll
    for (int q = 0; q < 4; q++) {
      int slot = tid + q * 512;
      rk[q] = *(const ush8*)(K + (slot >> 2) * 256 + d0 + (slot & 3) * 8);
    }
  };
  auto kwrite = [&]() {
#pragma unroll
    for (int q = 0; q < 4; q++) {
      int slot = tid + q * 512;
      *(ush8*)(&Kl[slot & 3][slot >> 2][0]) = rk[q];
    }
  };

  kload(0); kwrite(); __syncthreads();
  for (int s = 0; s < 8; s++) {
    if (s < 7) kload((s + 1) * 32);
    int ks = l >> 4;
    bf16x8 a[2], bb[4];
#pragma unroll
    for (int m = 0; m < 2; m++) a[m] = *(const bf16x8*)(&Ql[s][ks][m * 16 + (l & 15)][0]);
#pragma unroll
    for (int n = 0; n < 4; n++) bb[n] = *(const bf16x8*)(&Kl[ks][w * 64 + n * 16 + (l & 15)][0]);
#pragma unroll
    for (int m = 0; m < 2; m++)
#pragma unroll
      for (int n = 0; n < 4; n++) acc[m][n] = MFMA16(a[m], bb[n], acc[m][n]);
    if (s == 7) break;
    __syncthreads();
    kwrite();
    __syncthreads();
  }

  float gmax[2][4];
#pragma unroll
  for (int m = 0; m < 2; m++)
#pragma unroll
    for (int r = 0; r < 4; r++) {
      float v = fmaxf(fmaxf(acc[m][0][r], acc[m][1][r]), fmaxf(acc[m][2][r], acc[m][3][r]));
#pragma unroll
      for (int off = 1; off < 16; off <<= 1) v = fmaxf(v, __shfl_xor(v, off, 16));
      if ((l & 15) == 0) red[m * 16 + (l >> 4) * 4 + r][w] = v;
    }
  __syncthreads();
#pragma unroll
  for (int m = 0; m < 2; m++)
#pragma unroll
    for (int r = 0; r < 4; r++) {
      int sr = m * 16 + (l >> 4) * 4 + r;
      float g = red[sr][0];
#pragma unroll
      for (int ww = 1; ww < 8; ww++) g = fmaxf(g, red[sr][ww]);
      gmax[m][r] = g;
    }
  __syncthreads();
#pragma unroll
  for (int m = 0; m < 2; m++)
#pragma unroll
    for (int r = 0; r < 4; r++) {
      float ssum = 0.f;
#pragma unroll
      for (int n = 0; n < 4; n++) {
        float e = __expf(acc[m][n][r] - gmax[m][r]);
        acc[m][n][r] = e;
        ssum += e;
      }
#pragma unroll
      for (int off = 1; off < 16; off <<= 1) ssum += __shfl_xor(ssum, off, 16);
      if ((l & 15) == 0) red[m * 16 + (l >> 4) * 4 + r][w] = ssum;
    }
  __syncthreads();
#pragma unroll
  for (int m = 0; m < 2; m++)
#pragma unroll
    for (int r = 0; r < 4; r++) {
      int sr = m * 16 + (l >> 4) * 4 + r;
      float tot = 0.f;
#pragma unroll
      for (int ww = 0; ww < 8; ww++) tot += red[sr][ww];
      float sc = 0.0625f / tot;
#pragma unroll
      for (int n = 0; n < 4; n++)
        P[(s0 + sr) * 512 + w * 64 + n * 16 + (l & 15)] = f2b(acc[m][n][r] * sc);
    }
}

// =====================================================================
// 5) PV products
__global__ __launch_bounds__(512) void k_pv(const ushortT* __restrict__ P16,
                                            const ushortT* __restrict__ actT,
                                            float* __restrict__ pvv, float* __restrict__ pva,
                                            ushortT* __restrict__ vc16, ushortT* __restrict__ ac16) {
  __shared__ ushortT Al[4][32][8];
  __shared__ ushortT Bl[4][256][8];
  const int tid = threadIdx.x, l = tid & 63, w = tid >> 6;
  const int bx = blockIdx.x;
  const int p = bx >> 6, b = (bx >> 4) & 3, sblk = bx & 15;
  const int s0 = sblk * 32;
  const ushortT* A = P16 + p * 1048576 + b * 262144;
  const int vsel = (p == 0) ? 0 : (p == 2) ? 1 : 2;
  const ushortT* VT = actT + vsel * ACT_E + b * 131072;

  f32x4 acc[2][2] = {};
  ush8 ra, rb[2];
  int a_row = tid >> 2, a_seg = tid & 3;
  auto sload = [&](int t0) {
    if (tid < 128) ra = *(const ush8*)(A + (s0 + a_row) * 512 + t0 + a_seg * 8);
#pragma unroll
    for (int q = 0; q < 2; q++) {
      int slot = tid + q * 512;
      rb[q] = *(const ush8*)(VT + (slot >> 2) * 512 + t0 + (slot & 3) * 8);
    }
  };
  auto swrite = [&]() {
    if (tid < 128) *(ush8*)(&Al[a_seg][a_row][0]) = ra;
#pragma unroll
    for (int q = 0; q < 2; q++) {
      int slot = tid + q * 512;
      *(ush8*)(&Bl[slot & 3][slot >> 2][0]) = rb[q];
    }
  };

  sload(0); swrite(); __syncthreads();
  for (int s = 0; s < 16; s++) {
    if (s < 15) sload((s + 1) * 32);
    int ks = l >> 4;
    bf16x8 a[2], bb[2];
#pragma unroll
    for (int m = 0; m < 2; m++) a[m] = *(const bf16x8*)(&Al[ks][m * 16 + (l & 15)][0]);
#pragma unroll
    for (int n = 0; n < 2; n++) bb[n] = *(const bf16x8*)(&Bl[ks][w * 32 + n * 16 + (l & 15)][0]);
#pragma unroll
    for (int m = 0; m < 2; m++)
#pragma unroll
      for (int n = 0; n < 2; n++) acc[m][n] = MFMA16(a[m], bb[n], acc[m][n]);
    if (s == 15) break;
    __syncthreads();
    swrite();
    __syncthreads();
  }
#pragma unroll
  for (int m = 0; m < 2; m++)
#pragma unroll
    for (int n = 0; n < 2; n++)
#pragma unroll
      for (int r = 0; r < 4; r++) {
        int row = s0 + m * 16 + (l >> 4) * 4 + r;
        int col = w * 32 + n * 16 + (l & 15);
        int gi = (b * 512 + row) * 256 + col;
        float v = acc[m][n][r];
        if (p == 0) pvv[gi] = v;
        else if (p == 1) vc16[gi] = f2b(v);
        else if (p == 2) pva[gi] = v;
        else ac16[gi] = f2b(v);
      }
}

// =====================================================================
// 6) two linears + combine
__global__ __launch_bounds__(512) void k_lin4c(
    const ushortT* __restrict__ vc16, const ushortT* __restrict__ ac16,
    const ushortT* __restrict__ wT,
    const float* __restrict__ w5b, const float* __restrict__ w6b,
    const float* __restrict__ w7b, const float* __restrict__ w8b,
    const float* __restrict__ pvv, const float* __restrict__ pva,
    ushortT* __restrict__ cfv, ushortT* __restrict__ cfa) {
  __shared__ ushortT Al[4][32][8];
  __shared__ ushortT B1[4][256][8];
  __shared__ ushortT B2[4][256][8];
  const int tid = threadIdx.x, l = tid & 63, w = tid >> 6;
  const int bx = blockIdx.x;
  const int side = bx >> 6, sblk = bx & 63;
  const int s0 = sblk * 32;
  const ushortT* A = side ? ac16 : vc16;
  const ushortT* W1 = wT + (side ? 7 : 5) * WD_E;
  const ushortT* W2 = wT + (side ? 8 : 6) * WD_E;
  const float* bb1 = side ? w7b : w5b;
  const float* bb2 = side ? w8b : w6b;
  const float* pv = side ? pva : pvv;
  ushortT* out = side ? cfa : cfv;

  f32x4 acc1[2][2] = {}, acc2[2][2] = {};
  ush8 ra, rb1[2], rb2[2];
  int a_row = tid >> 2, a_seg = tid & 3;
  auto sload = [&](int k0) {
    if (tid < 128) ra = *(const ush8*)(A + (s0 + a_row) * 256 + k0 + a_seg * 8);
#pragma unroll
    for (int q = 0; q < 2; q++) {
      int slot = tid + q * 512;
      rb1[q] = *(const ush8*)(W1 + (slot >> 2) * 256 + k0 + (slot & 3) * 8);
      rb2[q] = *(const ush8*)(W2 + (slot >> 2) * 256 + k0 + (slot & 3) * 8);
    }
  };
  auto swrite = [&]() {
    if (tid < 128) *(ush8*)(&Al[a_seg][a_row][0]) = ra;
#pragma unroll
    for (int q = 0; q < 2; q++) {
      int slot = tid + q * 512;
      *(ush8*)(&B1[slot & 3][slot >> 2][0]) = rb1[q];
      *(ush8*)(&B2[slot & 3][slot >> 2][0]) = rb2[q];
    }
  };

  sload(0); swrite(); __syncthreads();
  for (int s = 0; s < 8; s++) {
    if (s < 7) sload((s + 1) * 32);
    int ks = l >> 4;
    bf16x8 a[2], x1[2], x2[2];
#pragma unroll
    for (int m = 0; m < 2; m++) a[m] = *(const bf16x8*)(&Al[ks][m * 16 + (l & 15)][0]);
#pragma unroll
    for (int n = 0; n < 2; n++) {
      x1[n] = *(const bf16x8*)(&B1[ks][w * 32 + n * 16 + (l & 15)][0]);
      x2[n] = *(const bf16x8*)(&B2[ks][w * 32 + n * 16 + (l & 15)][0]);
    }
#pragma unroll
    for (int m = 0; m < 2; m++)
#pragma unroll
      for (int n = 0; n < 2; n++) {
        acc1[m][n] = MFMA16(a[m], x1[n], acc1[m][n]);
        acc2[m][n] = MFMA16(a[m], x2[n], acc2[m][n]);
      }
    if (s == 7) break;
    __syncthreads();
    swrite();
    __syncthreads();
  }
#pragma unroll
  for (int m = 0; m < 2; m++)
#pragma unroll
    for (int n = 0; n < 2; n++)
#pragma unroll
      for (int r = 0; r < 4; r++) {
        int row = s0 + m * 16 + (l >> 4) * 4 + r;
        int col = w * 32 + n * 16 + (l & 15);
        int gi = row * 256 + col;
        float u1 = acc1[m][n][r] + bb1[col];
        float u2 = acc2[m][n][r] + bb2[col];
        out[gi] = f2b((1.f + u1) * pv[gi] + u2);
      }
}

// =====================================================================
// 7) bilinear v7: 64x128 wave tiles (2x LDS reuse), all conversions on the
// staging path.  m[r,ko] = sum_k A'[r,k] W[ko,k], A'[r,i*256+j]=cfv[r,i]cfa[r,j].
// grid 256 = ic(32) x mb(8) XCD-grouped by ic.  Block 256 rows x 256 ko,
// 512 thr, 8 waves 4M x 2N (wave tile 64 x 128).  32 K-steps of BK=64
// (8 i x 4 js, i outer).  A: reg-staged cfa scaled by cfv[r,i] (VALU on the
// latency-hidden staging path).  B: reg-staged from f32 bil_w, cvt_pk to
// bf16 (kills the separate cvt kernel).  Double-buffered A+B, one
// __syncthreads per step (all vmem consumed same-step).  f32 partials (32).
__global__ __launch_bounds__(512, 2) void k_bilinear7(
    const ushortT* __restrict__ cfa, const ushortT* __restrict__ cfv,
    const float* __restrict__ Wf, float* __restrict__ part) {
  // LDS: A 2x32768 @0; B 2x32768 @65536; cfv f32 [256][9] @131072. tot 140288.
  __shared__ char arena[140288];
  const int tid = threadIdx.x, l = tid & 63, w = tid >> 6;
  const int d = blockIdx.x;
  const int L = (d & 7) * 32 + (d >> 3);   // XCD-group: same-ic blocks share L2
  const int ic = L >> 3;          // 0..31
  const int mb = L & 7;           // 0..7
  const int r0 = mb * 256;
  const int icb = ic * 8;
  const int wr = w >> 1, wc = w & 1;   // 4(M) x 2(N); wave tile 64 x 128

  // ---- cfv slice -> LDS f32 [256][9] (pad 9 to spread banks)
  float* cfvl = (float*)(arena + 131072);
  if (tid < 256) {
    ush8 v = *(const ush8*)(cfv + (r0 + tid) * 256 + icb);
    float* dp = cfvl + tid * 9;
#pragma unroll
    for (int q = 0; q < 8; q++) dp[q] = b2f(v[q]);
  }

  // ---- staging geometry ----
  // Both tiles [256 rows][64 k] bf16 = 128 B/row, 32 KB.  XOR involution
  // lg = p ^ ((p>>7 & 7)<<4).  4 slots/thread each for A and B; thread
  // writes LINEAR phys p, sources from XOR-inverted logical addr.
  int pS[4], rowA[4];
  const char* gAsrc[4];
  const char* gBsrc[4];
#pragma unroll
  for (int s = 0; s < 4; s++) {
    int p = (tid + s * 512) * 16;
    int lg = p ^ (((p >> 7) & 7) << 4);
    int row = lg >> 7, colb = lg & 127;
    pS[s] = p;
    rowA[s] = row;
    gAsrc[s] = (const char*)cfa + (size_t)(r0 + row) * 512 + colb;              // bf16, +js*128
    gBsrc[s] = (const char*)Wf + ((size_t)row * 65536 + (size_t)icb * 256 + (colb >> 1)) * 4; // f32
  }

  // fragment read offsets (swizzled bytes), per kc half
  int aoff[2][4], boff[2][8];
#pragma unroll
  for (int m = 0; m < 4; m++) {
    int row = wr * 64 + m * 16 + (l & 15);
    int b0 = row * 128 + (l >> 4) * 16;
    int msk = (row & 7) << 4;
    aoff[0][m] = b0 ^ msk;
    aoff[1][m] = (b0 + 64) ^ msk;
  }
#pragma unroll
  for (int n = 0; n < 8; n++) {
    int row = wc * 128 + n * 16 + (l & 15);
    int b0 = row * 128 + (l >> 4) * 16;
    int msk = (row & 7) << 4;
    boff[0][n] = b0 ^ msk;
    boff[1][n] = (b0 + 64) ^ msk;
  }

  ush8 arg[4];     // raw cfa 16B per A slot
  f32x4 brg[8];    // raw W f32, 2 per B slot

  auto loadA = [&](int t) {
    int ja = (t & 3) << 7;   // js*128 bytes
#pragma unroll
    for (int s = 0; s < 4; s++) arg[s] = *(const ush8*)(gAsrc[s] + ja);
  };
  auto loadB = [&](int t) {
    int off = ((t >> 2) << 10) + ((t & 3) << 8);   // (i*256 + js*64)*4 bytes
#pragma unroll
    for (int s = 0; s < 4; s++) {
      brg[2 * s]     = *(const f32x4*)(gBsrc[s] + off);
      brg[2 * s + 1] = *(const f32x4*)(gBsrc[s] + off + 16);
    }
  };
  auto writeA = [&](int t, char* Ab) {
    int i = t >> 2;
#pragma unroll
    for (int s = 0; s < 4; s++) {
      float sc = cfvl[rowA[s] * 9 + i];
      bf16x8 as = scale8(__builtin_bit_cast(bf16x8, arg[s]), sc);
      *(bf16x8*)(Ab + pS[s]) = as;
    }
  };
  auto writeB = [&](char* Bb) {
#pragma unroll
    for (int s = 0; s < 4; s++) packB16(brg[2 * s], brg[2 * s + 1], Bb + pS[s]);
  };

  f32x4 macc[4][8] = {};

  // prologue: stage step 0 into buf0 (cfv must be visible before writeA)
  loadA(0); loadB(0);
  __syncthreads();
  writeA(0, arena);
  writeB(arena + 65536);
  __syncthreads();

#pragma unroll 2
  for (int t = 0; t < 32; t++) {
    char* Ab = arena + ((t & 1) << 15);
    char* Bb = arena + 65536 + ((t & 1) << 15);
    char* An = arena + (((t + 1) & 1) << 15);
    char* Bn = arena + 65536 + (((t + 1) & 1) << 15);

    // kc0 fragment reads
    bf16x8 a0[4], b0v[8];
#pragma unroll
    for (int m = 0; m < 4; m++) a0[m] = *(const bf16x8*)(Ab + aoff[0][m]);
#pragma unroll
    for (int n = 0; n < 8; n++) b0v[n] = *(const bf16x8*)(Bb + boff[0][n]);

    // prefetch next step into regs (latency hides under MFMA kc0)
    if (t < 31) { loadA(t + 1); loadB(t + 1); }

    __builtin_amdgcn_s_setprio(1);
#pragma unroll
    for (int m = 0; m < 4; m++)
#pragma unroll
      for (int n = 0; n < 8; n++) macc[m][n] = MFMA16(a0[m], b0v[n], macc[m][n]);
    __builtin_amdgcn_s_setprio(0);

    // convert + write next step to the other buffer (WAR-safe: its readers
    // finished before the barrier at the end of step t-1)
    if (t < 31) { writeA(t + 1, An); writeB(Bn); }

    // kc1 fragment reads
    bf16x8 a1[4], b1v[8];
#pragma unroll
    for (int m = 0; m < 4; m++) a1[m] = *(const bf16x8*)(Ab + aoff[1][m]);
#pragma unroll
    for (int n = 0; n < 8; n++) b1v[n] = *(const bf16x8*)(Bb + boff[1][n]);

    __builtin_amdgcn_s_setprio(1);
#pragma unroll
    for (int m = 0; m < 4; m++)
#pragma unroll
      for (int n = 0; n < 8; n++) macc[m][n] = MFMA16(a1[m], b1v[n], macc[m][n]);
    __builtin_amdgcn_s_setprio(0);

    __syncthreads();
  }

  // epilogue: store fp32 partial
  float* dst = part + (size_t)ic * 524288 + (size_t)r0 * 256;
#pragma unroll
  for (int m = 0; m < 4; m++)
#pragma unroll
    for (int n = 0; n < 8; n++)
#pragma unroll
      for (int r = 0; r < 4; r++)
        dst[(wr * 64 + m * 16 + ((l >> 4) << 2) + r) * 256 + wc * 128 + n * 16 + (l & 15)] =
            macc[m][n][r];
}

// =====================================================================
// 8) final gate + partial reduction over 32 ic-chunks
__global__ void k_final2(const float* __restrict__ part, const float* __restrict__ img,
                         const float* __restrict__ aud, const float* __restrict__ t_o,
                         float* __restrict__ out0, float* __restrict__ out1) {
  int i = blockIdx.x * 256 + threadIdx.x;
  float t = t_o[0];
  float4 m = {0.f, 0.f, 0.f, 0.f};
#pragma unroll
  for (int ic = 0; ic < 32; ic++) {
    float4 p = ((const float4*)(part + (size_t)ic * 524288))[i];
    m.x += p.x; m.y += p.y; m.z += p.z; m.w += p.w;
  }
  float4 a = ((const float4*)img)[i];
  float4 u = ((const float4*)aud)[i];
  float4 o0, o1;
  {
    float j = 1.f / (1.f + __expf(-m.x)); float Z = t * j * a.x + (1.f - j) * u.x;
    o0.x = Z + a.x; o1.x = Z + u.x;
  }
  {
    float j = 1.f / (1.f + __expf(-m.y)); float Z = t * j * a.y + (1.f - j) * u.y;
    o0.y = Z + a.y; o1.y = Z + u.y;
  }
  {
    float j = 1.f / (1.f + __expf(-m.z)); float Z = t * j * a.z + (1.f - j) * u.z;
    o0.z = Z + a.z; o1.z = Z + u.z;
  }
  {
    float j = 1.f / (1.f + __expf(-m.w)); float Z = t * j * a.w + (1.f - j) * u.w;
    o0.w = Z + a.w; o1.w = Z + u.w;
  }
  ((float4*)out0)[i] = o0;
  ((float4*)out1)[i] = o1;
}

// =====================================================================
extern "C" void kernel_launch(void* const* d_in, const int* in_sizes, int n_in,
                              void* d_out, int out_size, void* d_ws, size_t ws_size,
                              hipStream_t stream) {
  const float* img   = (const float*)d_in[0];
  const float* aud   = (const float*)d_in[1];
  const float* com   = (const float*)d_in[2];
  const float* qv_w  = (const float*)d_in[3];
  const float* qv_b  = (const float*)d_in[4];
  const float* qa_w  = (const float*)d_in[5];
  const float* qa_b  = (const float*)d_in[6];
  const float* kv_w  = (const float*)d_in[7];
  const float* kv_b  = (const float*)d_in[8];
  const float* ka_w  = (const float*)d_in[9];
  const float* ka_b  = (const float*)d_in[10];
  const float* cc_w  = (const float*)d_in[11];
  const float* cc_b  = (const float*)d_in[12];
  const float* w5_w  = (const float*)d_in[13];
  const float* w5_b  = (const float*)d_in[14];
  const float* w6_w  = (const float*)d_in[15];
  const float* w6_b  = (const float*)d_in[16];
  const float* w7_w  = (const float*)d_in[17];
  const float* w7_b  = (const float*)d_in[18];
  const float* w8_w  = (const float*)d_in[19];
  const float* w8_b  = (const float*)d_in[20];
  const float* bil_w = (const float*)d_in[21];
  const float* t_o   = (const float*)d_in[22];
  float* out = (float*)d_out;

  char* ws = (char*)d_ws;
  ushortT* act16  = (ushortT*)(ws + OFF_ACT16);
  ushortT* actT16 = (ushortT*)(ws + OFF_ACTT16);
  ushortT* w16t   = (ushortT*)(ws + OFF_W16T);
  ushortT* proj16 = (ushortT*)(ws + OFF_PROJ16);
  ushortT* P16    = (ushortT*)(ws + OFF_P16);
  ushortT* vc16   = (ushortT*)(ws + OFF_VC16);
  ushortT* ac16   = (ushortT*)(ws + OFF_AC16);
  float*   pvv32  = (float*)(ws + OFF_PVV32);
  float*   pva32  = (float*)(ws + OFF_PVA32);
  float*   part   = (float*)(ws + OFF_PART);
  ushortT* cfv16  = (ushortT*)(ws + OFF_CFV16);
  ushortT* cfa16  = (ushortT*)(ws + OFF_CFA16);

  k_cvt_acts<<<384, 256, 0, stream>>>(img, aud, com, act16);
  k_transpose<<<528, 256, 0, stream>>>(img, aud, com, qv_w, qa_w, kv_w, ka_w, cc_w,
                                       w5_w, w6_w, w7_w, w8_w, actT16, w16t);
  k_linear5<<<320, 512, 0, stream>>>(act16, w16t, qv_b, qa_b, kv_b, ka_b, cc_b, proj16);
  k_attn<<<256, 512, 0, stream>>>(proj16, P16);
  k_pv<<<256, 512, 0, stream>>>(P16, actT16, pvv32, pva32, vc16, ac16);
  k_lin4c<<<128, 512, 0, stream>>>(vc16, ac16, w16t, w5_b, w6_b, w7_b, w8_b,
                                   pvv32, pva32, cfv16, cfa16);
  k_bilinear7<<<256, 512, 0, stream>>>(cfa16, cfv16, bil_w, part);
  k_final2<<<512, 256, 0, stream>>>(part, img, aud, t_o, out, out + 524288);
}

// Round 8
// 148.407 us; speedup vs baseline: 2.9807x; 2.9807x over previous
//
#include <hip/hip_runtime.h>
#include <hip/hip_bf16.h>

// ---------- types ----------
typedef unsigned short ushortT;
typedef __bf16 bf16x8 __attribute__((ext_vector_type(8)));
typedef float f32x4 __attribute__((ext_vector_type(4)));
typedef ushortT ush8 __attribute__((ext_vector_type(8)));
typedef ushortT ush4 __attribute__((ext_vector_type(4)));

#define MFMA16(a, b, c) __builtin_amdgcn_mfma_f32_16x16x32_bf16((a), (b), (c), 0, 0, 0)

__device__ __forceinline__ ushortT f2b(float f) {
  __hip_bfloat16 h = __float2bfloat16(f);
  return __builtin_bit_cast(ushortT, h);
}
__device__ __forceinline__ float b2f(ushortT u) {
  __hip_bfloat16 h = __builtin_bit_cast(__hip_bfloat16, u);
  return __bfloat162float(h);
}

// async global->LDS, 16B per lane
__device__ __forceinline__ void async16(const void* g, void* l) {
  __builtin_amdgcn_global_load_lds((const __attribute__((address_space(1))) unsigned int*)g,
                                   (__attribute__((address_space(3))) unsigned int*)l, 16, 0, 0);
}

// scale 8 bf16 by scalar s in f32, round back to bf16 (v_cvt_pk_bf16_f32)
__device__ __forceinline__ bf16x8 scale8(bf16x8 a, float s) {
  union { bf16x8 v; unsigned int u[4]; } in, out;
  in.v = a;
#pragma unroll
  for (int p = 0; p < 4; p++) {
    float lo = __builtin_bit_cast(float, in.u[p] << 16);
    float hi = __builtin_bit_cast(float, in.u[p] & 0xffff0000u);
    lo *= s;
    hi *= s;
    unsigned int r;
    asm("v_cvt_pk_bf16_f32 %0, %1, %2" : "=v"(r) : "v"(lo), "v"(hi));
    out.u[p] = r;
  }
  return out.v;
}

// ---------- problem dims ----------
// B=4, S=512, D=256, ROWS = B*S = 2048
#define ACT_E 524288   // 2048*256 elements
#define WD_E  65536    // 256*256

// ---------- ws layout (bytes) ----------
// identical footprint to the proven R2-R6 map (69,206,016 bytes)
#define OFF_ACT16   0u          // 3 * ACT_E * 2 = 3145728
#define OFF_ACTT16  3145728u
#define OFF_W16T    6291456u
#define OFF_PROJ16  7471104u
#define OFF_P16     12713984u
#define OFF_VC16    21102592u
#define OFF_AC16    22151168u
#define OFF_PVV32   23199744u
#define OFF_PVA32   25296896u   // ends 27394048
#define OFF_PART    0u          // bf16: 32 * 524288 * 2 = 33554432 (overlaps dead transients)
#define OFF_BIL16   33554432u   // 33554432 bytes, ends 67108864
#define OFF_CFV16   67108864u   // ACT_E*2
#define OFF_CFA16   68157440u   // ends 69206016

// =====================================================================
// 1) convert img/audio/common fp32 -> bf16 (same layout)
__global__ void k_cvt_acts(const float* __restrict__ img, const float* __restrict__ aud,
                           const float* __restrict__ com, ushortT* __restrict__ dst) {
  int i4 = blockIdx.x * 256 + threadIdx.x;
#pragma unroll
  for (int q = 0; q < 4; q++) {
    int idx4 = i4 + q * 98304;
    int flat = idx4 * 4;
    const float* src;
    int off;
    if (flat < 524288)        { src = img; off = flat; }
    else if (flat < 1048576)  { src = aud; off = flat - 524288; }
    else                      { src = com; off = flat - 1048576; }
    float4 v = *(const float4*)(src + off);
    ush4 u = { f2b(v.x), f2b(v.y), f2b(v.z), f2b(v.w) };
    *(ush4*)(dst + idx4 * 4) = u;
  }
}

// 2) convert bil_w fp32 -> bf16
__global__ void k_cvt_bil(const float* __restrict__ bil, ushortT* __restrict__ dst) {
  int i4 = blockIdx.x * 256 + threadIdx.x;
#pragma unroll
  for (int q = 0; q < 8; q++) {
    int idx4 = i4 + q * 524288;
    float4 v = *(const float4*)(bil + idx4 * 4);
    ush4 u = { f2b(v.x), f2b(v.y), f2b(v.z), f2b(v.w) };
    *(ush4*)(dst + idx4 * 4) = u;
  }
}

// 3) transpose+convert
__global__ void k_transpose(const float* __restrict__ img, const float* __restrict__ aud,
                            const float* __restrict__ com,
                            const float* w0, const float* w1, const float* w2,
                            const float* w3, const float* w4, const float* w5,
                            const float* w6, const float* w7, const float* w8,
                            ushortT* __restrict__ actT, ushortT* __restrict__ wT) {
  __shared__ ushortT tl[64][72];
  int tid = threadIdx.x;
  int bx = blockIdx.x;
  const float* src;
  ushortT* dst;
  int R, C, r0, c0;
  if (bx < 384) {
    int inst = bx >> 5, tile = bx & 31;
    int act = inst >> 2, bb = inst & 3;
    src = (act == 0 ? img : (act == 1 ? aud : com)) + bb * 131072;
    dst = actT + act * 524288 + bb * 131072;
    R = 512; C = 256;
    r0 = (tile >> 2) * 64; c0 = (tile & 3) * 64;
  } else {
    int bw = bx - 384;
    int w = bw >> 4, tile = bw & 15;
    const float* s;
    switch (w) {
      case 0: s = w0; break; case 1: s = w1; break; case 2: s = w2; break;
      case 3: s = w3; break; case 4: s = w4; break; case 5: s = w5; break;
      case 6: s = w6; break; case 7: s = w7; break; default: s = w8; break;
    }
    src = s;
    dst = wT + w * 65536;
    R = 256; C = 256;
    r0 = (tile >> 2) * 64; c0 = (tile & 3) * 64;
  }
#pragma unroll
  for (int q = 0; q < 4; q++) {
    int rr = q * 16 + (tid >> 4);
    int cs = (tid & 15) * 4;
    float4 v = *(const float4*)(src + (r0 + rr) * C + c0 + cs);
    tl[rr][cs + 0] = f2b(v.x);
    tl[rr][cs + 1] = f2b(v.y);
    tl[rr][cs + 2] = f2b(v.z);
    tl[rr][cs + 3] = f2b(v.w);
  }
  __syncthreads();
#pragma unroll
  for (int q = 0; q < 4; q++) {
    int cc = q * 16 + (tid >> 4);
    int rs = (tid & 15) * 4;
    ush4 u = { tl[rs + 0][cc], tl[rs + 1][cc], tl[rs + 2][cc], tl[rs + 3][cc] };
    *(ush4*)(dst + (c0 + cc) * R + r0 + rs) = u;
  }
}

// =====================================================================
// 4) five input linears
__global__ __launch_bounds__(512) void k_linear5(
    const ushortT* __restrict__ act16, const ushortT* __restrict__ wT,
    const float* __restrict__ b0, const float* __restrict__ b1,
    const float* __restrict__ b2, const float* __restrict__ b3,
    const float* __restrict__ b4, ushortT* __restrict__ proj16) {
  __shared__ ushortT Al[4][32][8];
  __shared__ ushortT Bl[4][256][8];
  const int tid = threadIdx.x, l = tid & 63, w = tid >> 6;
  const int bx = blockIdx.x;
  const int op = bx >> 6, sblk = bx & 63;
  const int s0 = sblk * 32;
  const int xsel = (op == 4) ? 2 : (op & 1);
  const ushortT* X = act16 + xsel * ACT_E;
  const ushortT* W = wT + op * WD_E;
  const float* bias = op == 0 ? b0 : op == 1 ? b1 : op == 2 ? b2 : op == 3 ? b3 : b4;
  ushortT* out = proj16 + op * ACT_E;

  f32x4 acc[2][2] = {};
  ush8 ra, rb[2];
  int a_row = tid >> 2, a_seg = tid & 3;

  auto sload = [&](int k0) {
    if (tid < 128) ra = *(const ush8*)(X + (s0 + a_row) * 256 + k0 + a_seg * 8);
#pragma unroll
    for (int q = 0; q < 2; q++) {
      int slot = tid + q * 512;
      rb[q] = *(const ush8*)(W + (slot >> 2) * 256 + k0 + (slot & 3) * 8);
    }
  };
  auto swrite = [&]() {
    if (tid < 128) *(ush8*)(&Al[a_seg][a_row][0]) = ra;
#pragma unroll
    for (int q = 0; q < 2; q++) {
      int slot = tid + q * 512;
      *(ush8*)(&Bl[slot & 3][slot >> 2][0]) = rb[q];
    }
  };

  sload(0); swrite(); __syncthreads();
  for (int s = 0; s < 8; s++) {
    if (s < 7) sload((s + 1) * 32);
    int ks = l >> 4;
    bf16x8 a[2], bb[2];
#pragma unroll
    for (int m = 0; m < 2; m++) a[m] = *(const bf16x8*)(&Al[ks][m * 16 + (l & 15)][0]);
#pragma unroll
    for (int n = 0; n < 2; n++) bb[n] = *(const bf16x8*)(&Bl[ks][w * 32 + n * 16 + (l & 15)][0]);
#pragma unroll
    for (int m = 0; m < 2; m++)
#pragma unroll
      for (int n = 0; n < 2; n++) acc[m][n] = MFMA16(a[m], bb[n], acc[m][n]);
    if (s == 7) break;
    __syncthreads();
    swrite();
    __syncthreads();
  }
#pragma unroll
  for (int m = 0; m < 2; m++)
#pragma unroll
    for (int n = 0; n < 2; n++)
#pragma unroll
      for (int r = 0; r < 4; r++) {
        int row = s0 + m * 16 + (l >> 4) * 4 + r;
        int col = w * 32 + n * 16 + (l & 15);
        out[row * 256 + col] = f2b(acc[m][n][r] + bias[col]);
      }
}

// =====================================================================
// 5) attention: P = softmax(Q K^T) * (1/16)
__global__ __launch_bounds__(512) void k_attn(const ushortT* __restrict__ proj16,
                                              ushortT* __restrict__ P16) {
  __shared__ ushortT Ql[8][4][32][8];
  __shared__ ushortT Kl[4][512][8];
  __shared__ float red[32][8];
  const int tid = threadIdx.x, l = tid & 63, w = tid >> 6;
  const int bx = blockIdx.x;
  const int p = bx >> 6, b = (bx >> 4) & 3, sblk = bx & 15;
  const int s0 = sblk * 32;
  const int qsel = (p < 2) ? 0 : 1;
  const int ksel = (p == 0) ? 2 : (p == 2) ? 3 : 4;
  const ushortT* Q = proj16 + qsel * ACT_E + b * 131072;
  const ushortT* K = proj16 + ksel * ACT_E + b * 131072;
  ushortT* P = P16 + p * 1048576 + b * 262144;

#pragma unroll
  for (int q = 0; q < 2; q++) {
    int slot = tid + q * 512;
    int row = slot >> 5, seg = slot & 31;
    ush8 v = *(const ush8*)(Q + (s0 + row) * 256 + seg * 8);
    *(ush8*)(&Ql[seg >> 2][seg & 3][row][0]) = v;
  }

  f32x4 acc[2][4] = {};
  ush8 rk[4];
  auto kload = [&](int d0) {
#pragma unroll
    for (int q = 0; q < 4; q++) {
      int slot = tid + q * 512;
      rk[q] = *(const ush8*)(K + (slot >> 2) * 256 + d0 + (slot & 3) * 8);
    }
  };
  auto kwrite = [&]() {
#pragma unroll
    for (int q = 0; q < 4; q++) {
      int slot = tid + q * 512;
      *(ush8*)(&Kl[slot & 3][slot >> 2][0]) = rk[q];
    }
  };

  kload(0); kwrite(); __syncthreads();
  for (int s = 0; s < 8; s++) {
    if (s < 7) kload((s + 1) * 32);
    int ks = l >> 4;
    bf16x8 a[2], bb[4];
#pragma unroll
    for (int m = 0; m < 2; m++) a[m] = *(const bf16x8*)(&Ql[s][ks][m * 16 + (l & 15)][0]);
#pragma unroll
    for (int n = 0; n < 4; n++) bb[n] = *(const bf16x8*)(&Kl[ks][w * 64 + n * 16 + (l & 15)][0]);
#pragma unroll
    for (int m = 0; m < 2; m++)
#pragma unroll
      for (int n = 0; n < 4; n++) acc[m][n] = MFMA16(a[m], bb[n], acc[m][n]);
    if (s == 7) break;
    __syncthreads();
    kwrite();
    __syncthreads();
  }

  float gmax[2][4];
#pragma unroll
  for (int m = 0; m < 2; m++)
#pragma unroll
    for (int r = 0; r < 4; r++) {
      float v = fmaxf(fmaxf(acc[m][0][r], acc[m][1][r]), fmaxf(acc[m][2][r], acc[m][3][r]));
#pragma unroll
      for (int off = 1; off < 16; off <<= 1) v = fmaxf(v, __shfl_xor(v, off, 16));
      if ((l & 15) == 0) red[m * 16 + (l >> 4) * 4 + r][w] = v;
    }
  __syncthreads();
#pragma unroll
  for (int m = 0; m < 2; m++)
#pragma unroll
    for (int r = 0; r < 4; r++) {
      int sr = m * 16 + (l >> 4) * 4 + r;
      float g = red[sr][0];
#pragma unroll
      for (int ww = 1; ww < 8; ww++) g = fmaxf(g, red[sr][ww]);
      gmax[m][r] = g;
    }
  __syncthreads();
#pragma unroll
  for (int m = 0; m < 2; m++)
#pragma unroll
    for (int r = 0; r < 4; r++) {
      float ssum = 0.f;
#pragma unroll
      for (int n = 0; n < 4; n++) {
        float e = __expf(acc[m][n][r] - gmax[m][r]);
        acc[m][n][r] = e;
        ssum += e;
      }
#pragma unroll
      for (int off = 1; off < 16; off <<= 1) ssum += __shfl_xor(ssum, off, 16);
      if ((l & 15) == 0) red[m * 16 + (l >> 4) * 4 + r][w] = ssum;
    }
  __syncthreads();
#pragma unroll
  for (int m = 0; m < 2; m++)
#pragma unroll
    for (int r = 0; r < 4; r++) {
      int sr = m * 16 + (l >> 4) * 4 + r;
      float tot = 0.f;
#pragma unroll
      for (int ww = 0; ww < 8; ww++) tot += red[sr][ww];
      float sc = 0.0625f / tot;
#pragma unroll
      for (int n = 0; n < 4; n++)
        P[(s0 + sr) * 512 + w * 64 + n * 16 + (l & 15)] = f2b(acc[m][n][r] * sc);
    }
}

// =====================================================================
// 6) PV products
__global__ __launch_bounds__(512) void k_pv(const ushortT* __restrict__ P16,
                                            const ushortT* __restrict__ actT,
                                            float* __restrict__ pvv, float* __restrict__ pva,
                                            ushortT* __restrict__ vc16, ushortT* __restrict__ ac16) {
  __shared__ ushortT Al[4][32][8];
  __shared__ ushortT Bl[4][256][8];
  const int tid = threadIdx.x, l = tid & 63, w = tid >> 6;
  const int bx = blockIdx.x;
  const int p = bx >> 6, b = (bx >> 4) & 3, sblk = bx & 15;
  const int s0 = sblk * 32;
  const ushortT* A = P16 + p * 1048576 + b * 262144;
  const int vsel = (p == 0) ? 0 : (p == 2) ? 1 : 2;
  const ushortT* VT = actT + vsel * ACT_E + b * 131072;

  f32x4 acc[2][2] = {};
  ush8 ra, rb[2];
  int a_row = tid >> 2, a_seg = tid & 3;
  auto sload = [&](int t0) {
    if (tid < 128) ra = *(const ush8*)(A + (s0 + a_row) * 512 + t0 + a_seg * 8);
#pragma unroll
    for (int q = 0; q < 2; q++) {
      int slot = tid + q * 512;
      rb[q] = *(const ush8*)(VT + (slot >> 2) * 512 + t0 + (slot & 3) * 8);
    }
  };
  auto swrite = [&]() {
    if (tid < 128) *(ush8*)(&Al[a_seg][a_row][0]) = ra;
#pragma unroll
    for (int q = 0; q < 2; q++) {
      int slot = tid + q * 512;
      *(ush8*)(&Bl[slot & 3][slot >> 2][0]) = rb[q];
    }
  };

  sload(0); swrite(); __syncthreads();
  for (int s = 0; s < 16; s++) {
    if (s < 15) sload((s + 1) * 32);
    int ks = l >> 4;
    bf16x8 a[2], bb[2];
#pragma unroll
    for (int m = 0; m < 2; m++) a[m] = *(const bf16x8*)(&Al[ks][m * 16 + (l & 15)][0]);
#pragma unroll
    for (int n = 0; n < 2; n++) bb[n] = *(const bf16x8*)(&Bl[ks][w * 32 + n * 16 + (l & 15)][0]);
#pragma unroll
    for (int m = 0; m < 2; m++)
#pragma unroll
      for (int n = 0; n < 2; n++) acc[m][n] = MFMA16(a[m], bb[n], acc[m][n]);
    if (s == 15) break;
    __syncthreads();
    swrite();
    __syncthreads();
  }
#pragma unroll
  for (int m = 0; m < 2; m++)
#pragma unroll
    for (int n = 0; n < 2; n++)
#pragma unroll
      for (int r = 0; r < 4; r++) {
        int row = s0 + m * 16 + (l >> 4) * 4 + r;
        int col = w * 32 + n * 16 + (l & 15);
        int gi = (b * 512 + row) * 256 + col;
        float v = acc[m][n][r];
        if (p == 0) pvv[gi] = v;
        else if (p == 1) vc16[gi] = f2b(v);
        else if (p == 2) pva[gi] = v;
        else ac16[gi] = f2b(v);
      }
}

// =====================================================================
// 7) two linears + combine
__global__ __launch_bounds__(512) void k_lin4c(
    const ushortT* __restrict__ vc16, const ushortT* __restrict__ ac16,
    const ushortT* __restrict__ wT,
    const float* __restrict__ w5b, const float* __restrict__ w6b,
    const float* __restrict__ w7b, const float* __restrict__ w8b,
    const float* __restrict__ pvv, const float* __restrict__ pva,
    ushortT* __restrict__ cfv, ushortT* __restrict__ cfa) {
  __shared__ ushortT Al[4][32][8];
  __shared__ ushortT B1[4][256][8];
  __shared__ ushortT B2[4][256][8];
  const int tid = threadIdx.x, l = tid & 63, w = tid >> 6;
  const int bx = blockIdx.x;
  const int side = bx >> 6, sblk = bx & 63;
  const int s0 = sblk * 32;
  const ushortT* A = side ? ac16 : vc16;
  const ushortT* W1 = wT + (side ? 7 : 5) * WD_E;
  const ushortT* W2 = wT + (side ? 8 : 6) * WD_E;
  const float* bb1 = side ? w7b : w5b;
  const float* bb2 = side ? w8b : w6b;
  const float* pv = side ? pva : pvv;
  ushortT* out = side ? cfa : cfv;

  f32x4 acc1[2][2] = {}, acc2[2][2] = {};
  ush8 ra, rb1[2], rb2[2];
  int a_row = tid >> 2, a_seg = tid & 3;
  auto sload = [&](int k0) {
    if (tid < 128) ra = *(const ush8*)(A + (s0 + a_row) * 256 + k0 + a_seg * 8);
#pragma unroll
    for (int q = 0; q < 2; q++) {
      int slot = tid + q * 512;
      rb1[q] = *(const ush8*)(W1 + (slot >> 2) * 256 + k0 + (slot & 3) * 8);
      rb2[q] = *(const ush8*)(W2 + (slot >> 2) * 256 + k0 + (slot & 3) * 8);
    }
  };
  auto swrite = [&]() {
    if (tid < 128) *(ush8*)(&Al[a_seg][a_row][0]) = ra;
#pragma unroll
    for (int q = 0; q < 2; q++) {
      int slot = tid + q * 512;
      *(ush8*)(&B1[slot & 3][slot >> 2][0]) = rb1[q];
      *(ush8*)(&B2[slot & 3][slot >> 2][0]) = rb2[q];
    }
  };

  sload(0); swrite(); __syncthreads();
  for (int s = 0; s < 8; s++) {
    if (s < 7) sload((s + 1) * 32);
    int ks = l >> 4;
    bf16x8 a[2], x1[2], x2[2];
#pragma unroll
    for (int m = 0; m < 2; m++) a[m] = *(const bf16x8*)(&Al[ks][m * 16 + (l & 15)][0]);
#pragma unroll
    for (int n = 0; n < 2; n++) {
      x1[n] = *(const bf16x8*)(&B1[ks][w * 32 + n * 16 + (l & 15)][0]);
      x2[n] = *(const bf16x8*)(&B2[ks][w * 32 + n * 16 + (l & 15)][0]);
    }
#pragma unroll
    for (int m = 0; m < 2; m++)
#pragma unroll
      for (int n = 0; n < 2; n++) {
        acc1[m][n] = MFMA16(a[m], x1[n], acc1[m][n]);
        acc2[m][n] = MFMA16(a[m], x2[n], acc2[m][n]);
      }
    if (s == 7) break;
    __syncthreads();
    swrite();
    __syncthreads();
  }
#pragma unroll
  for (int m = 0; m < 2; m++)
#pragma unroll
    for (int n = 0; n < 2; n++)
#pragma unroll
      for (int r = 0; r < 4; r++) {
        int row = s0 + m * 16 + (l >> 4) * 4 + r;
        int col = w * 32 + n * 16 + (l & 15);
        int gi = row * 256 + col;
        float u1 = acc1[m][n][r] + bb1[col];
        float u2 = acc2[m][n][r] + bb2[col];
        out[gi] = f2b((1.f + u1) * pv[gi] + u2);
      }
}

// =====================================================================
// 8) bilinear v8: 64x128 wave tiles (R7 geometry) with a SPILL-PROOF
// register budget.  m[r,ko] = sum_k A'[r,k] W[ko,k], A'=cfv[r,i]*cfa[r,j].
// grid 256 = ic(32) x mb(8), XCD-grouped by ic (4 x 1MB W slices per XCD L2).
// Block 256 rows x 256 ko, 512 thr, 8 waves 4M x 2N (wave 64x128).
// 32 K-steps of BK=64 (i = t>>2 outer, j-block = t&3).
//  - A: reg-staged cfa (arg[4]) scaled by cfv[r,i] on the LDS-write path.
//  - B: global_load_lds from bf16 W (zero staging registers).
//  - dbuf, one __syncthreads/step, issue-early staging.
//  - launch_bounds(512,1): 256 VGPR cap; B-MFMAs in groups of 4 keep
//    peak live regs ~230 (R7 failed at the 128-reg cap: full acc spill).
__global__ __launch_bounds__(512, 1) void k_bilinear8(
    const ushortT* __restrict__ cfa, const ushortT* __restrict__ cfv,
    const ushortT* __restrict__ W, ushortT* __restrict__ part) {
  // LDS: A dbuf 2x32768 @0; B dbuf 2x32768 @65536; cfv f32 [256][9] @131072.
  __shared__ char arena[140288];
  const int tid = threadIdx.x, l = tid & 63, w = tid >> 6;
  const int d = blockIdx.x;
  const int L = (d & 7) * 32 + (d >> 3);
  const int ic = L >> 3;          // 0..31
  const int mb = L & 7;           // 0..7
  const int r0 = mb * 256;
  const int icb = ic * 8;
  const int wr = w >> 1, wc = w & 1;   // 4(M) x 2(N); wave tile 64 x 128

  // ---- cfv slice -> LDS f32 [256][9]
  float* cfvl = (float*)(arena + 131072);
  if (tid < 256) {
    ush8 v = *(const ush8*)(cfv + (size_t)(r0 + tid) * 256 + icb);
    float* dp = cfvl + tid * 9;
#pragma unroll
    for (int q = 0; q < 8; q++) dp[q] = b2f(v[q]);
  }

  // ---- staging geometry: tiles [256 rows][64 k] bf16, 128 B/row, 32 KB.
  // phys p linear; logical lg = p ^ ((p>>7 & 7)<<4); 4 slots/thread.
  int pS[4], aOff[4], bOff[4], cvIdx[4];
#pragma unroll
  for (int s = 0; s < 4; s++) {
    int p = (tid + s * 512) * 16;
    int lg = p ^ (((p >> 7) & 7) << 4);
    int row = lg >> 7, colb = lg & 127;
    pS[s] = p;
    cvIdx[s] = row * 9;
    aOff[s] = (r0 + row) * 512 + colb;                  // bytes into cfa
    bOff[s] = row * 131072 + icb * 512 + colb;          // bytes into W (row = ko)
  }
  const char* cfaB = (const char*)cfa;
  const char* WB = (const char*)W;

  // fragment read offsets (swizzled bytes), per kc half
  int aoff[2][4], boff[2][8];
#pragma unroll
  for (int m = 0; m < 4; m++) {
    int row = wr * 64 + m * 16 + (l & 15);
    int b0 = row * 128 + (l >> 4) * 16;
    int msk = (row & 7) << 4;
    aoff[0][m] = b0 ^ msk;
    aoff[1][m] = (b0 + 64) ^ msk;
  }
#pragma unroll
  for (int n = 0; n < 8; n++) {
    int row = wc * 128 + n * 16 + (l & 15);
    int b0 = row * 128 + (l >> 4) * 16;
    int msk = (row & 7) << 4;
    boff[0][n] = b0 ^ msk;
    boff[1][n] = (b0 + 64) ^ msk;
  }

  ush8 arg[4];
  auto loadA = [&](int t) {
    int ja = (t & 3) << 7;                        // j-block * 128 bytes
#pragma unroll
    for (int s = 0; s < 4; s++) arg[s] = *(const ush8*)(cfaB + aOff[s] + ja);
  };
  auto gloadB = [&](int t, char* Bb) {
    int jb = ((t >> 2) << 9) + ((t & 3) << 7);    // i*512 + j-block*128 bytes
#pragma unroll
    for (int s = 0; s < 4; s++) async16(WB + bOff[s] + jb, Bb + pS[s]);
  };
  auto writeA = [&](int t, char* Ab) {
    int ii = t >> 2;
#pragma unroll
    for (int s = 0; s < 4; s++) {
      float sc = cfvl[cvIdx[s] + ii];
      *(bf16x8*)(Ab + pS[s]) = scale8(__builtin_bit_cast(bf16x8, arg[s]), sc);
    }
  };

  f32x4 macc[4][8] = {};

  // prologue: step 0 into buf0
  loadA(0);
  gloadB(0, arena + 65536);
  __syncthreads();          // cfv visible; B(0) vmem drained by implicit waitcnt
  writeA(0, arena);
  __syncthreads();          // A(0) visible

  for (int t = 0; t < 32; t++) {
    char* Ab = arena + ((t & 1) << 15);
    char* Bb = arena + 65536 + ((t & 1) << 15);
    char* An = arena + (((t + 1) & 1) << 15);
    char* Bn = arena + 65536 + (((t + 1) & 1) << 15);

    bf16x8 a0[4];
#pragma unroll
    for (int m = 0; m < 4; m++) a0[m] = *(const bf16x8*)(Ab + aoff[0][m]);

    // issue-early staging for t+1 (WAR-safe: buf^1's readers finished
    // before the end-of-(t-1) barrier)
    if (t < 31) { loadA(t + 1); gloadB(t + 1, Bn); }

    // kc0, B frags in two groups of 4 (limits live regs)
    {
      bf16x8 bl[4];
#pragma unroll
      for (int n = 0; n < 4; n++) bl[n] = *(const bf16x8*)(Bb + boff[0][n]);
      __builtin_amdgcn_s_setprio(1);
#pragma unroll
      for (int m = 0; m < 4; m++)
#pragma unroll
        for (int n = 0; n < 4; n++) macc[m][n] = MFMA16(a0[m], bl[n], macc[m][n]);
      __builtin_amdgcn_s_setprio(0);
    }
    {
      bf16x8 bh[4];
#pragma unroll
      for (int n = 0; n < 4; n++) bh[n] = *(const bf16x8*)(Bb + boff[0][n + 4]);
      __builtin_amdgcn_s_setprio(1);
#pragma unroll
      for (int m = 0; m < 4; m++)
#pragma unroll
        for (int n = 0; n < 4; n++) macc[m][n + 4] = MFMA16(a0[m], bh[n], macc[m][n + 4]);
      __builtin_amdgcn_s_setprio(0);
    }

    // scale+write next A tile (VALU on the staging path, hidden under MFMA)
    if (t < 31) writeA(t + 1, An);

    // kc1
    bf16x8 a1[4];
#pragma unroll
    for (int m = 0; m < 4; m++) a1[m] = *(const bf16x8*)(Ab + aoff[1][m]);
    {
      bf16x8 bl[4];
#pragma unroll
      for (int n = 0; n < 4; n++) bl[n] = *(const bf16x8*)(Bb + boff[1][n]);
      __builtin_amdgcn_s_setprio(1);
#pragma unroll
      for (int m = 0; m < 4; m++)
#pragma unroll
        for (int n = 0; n < 4; n++) macc[m][n] = MFMA16(a1[m], bl[n], macc[m][n]);
      __builtin_amdgcn_s_setprio(0);
    }
    {
      bf16x8 bh[4];
#pragma unroll
      for (int n = 0; n < 4; n++) bh[n] = *(const bf16x8*)(Bb + boff[1][n + 4]);
      __builtin_amdgcn_s_setprio(1);
#pragma unroll
      for (int m = 0; m < 4; m++)
#pragma unroll
        for (int n = 0; n < 4; n++) macc[m][n + 4] = MFMA16(a1[m], bh[n], macc[m][n + 4]);
      __builtin_amdgcn_s_setprio(0);
    }

    __syncthreads();   // drains vmcnt(0): B(t+1) landed; A(t+1) writes visible
  }

  // epilogue: bf16 partial
  ushortT* dst = part + (size_t)ic * 524288 + (size_t)r0 * 256;
#pragma unroll
  for (int m = 0; m < 4; m++)
#pragma unroll
    for (int n = 0; n < 8; n++)
#pragma unroll
      for (int r = 0; r < 4; r++)
        dst[(wr * 64 + m * 16 + ((l >> 4) << 2) + r) * 256 + wc * 128 + n * 16 + (l & 15)] =
            f2b(macc[m][n][r]);
}

// =====================================================================
// 9) final gate + partial reduction over 32 bf16 ic-chunks
__global__ void k_final2(const ushortT* __restrict__ part, const float* __restrict__ img,
                         const float* __restrict__ aud, const float* __restrict__ t_o,
                         float* __restrict__ out0, float* __restrict__ out1) {
  int i = blockIdx.x * 256 + threadIdx.x;   // 131072 groups of 4 elems
  float t = t_o[0];
  float4 m = {0.f, 0.f, 0.f, 0.f};
#pragma unroll
  for (int ic = 0; ic < 32; ic++) {
    ush4 p = *(const ush4*)(part + (size_t)ic * 524288 + (size_t)i * 4);
    m.x += b2f(p[0]); m.y += b2f(p[1]); m.z += b2f(p[2]); m.w += b2f(p[3]);
  }
  float4 a = ((const float4*)img)[i];
  float4 u = ((const float4*)aud)[i];
  float4 o0, o1;
  {
    float j = 1.f / (1.f + __expf(-m.x)); float Z = t * j * a.x + (1.f - j) * u.x;
    o0.x = Z + a.x; o1.x = Z + u.x;
  }
  {
    float j = 1.f / (1.f + __expf(-m.y)); float Z = t * j * a.y + (1.f - j) * u.y;
    o0.y = Z + a.y; o1.y = Z + u.y;
  }
  {
    float j = 1.f / (1.f + __expf(-m.z)); float Z = t * j * a.z + (1.f - j) * u.z;
    o0.z = Z + a.z; o1.z = Z + u.z;
  }
  {
    float j = 1.f / (1.f + __expf(-m.w)); float Z = t * j * a.w + (1.f - j) * u.w;
    o0.w = Z + a.w; o1.w = Z + u.w;
  }
  ((float4*)out0)[i] = o0;
  ((float4*)out1)[i] = o1;
}

// =====================================================================
extern "C" void kernel_launch(void* const* d_in, const int* in_sizes, int n_in,
                              void* d_out, int out_size, void* d_ws, size_t ws_size,
                              hipStream_t stream) {
  const float* img   = (const float*)d_in[0];
  const float* aud   = (const float*)d_in[1];
  const float* com   = (const float*)d_in[2];
  const float* qv_w  = (const float*)d_in[3];
  const float* qv_b  = (const float*)d_in[4];
  const float* qa_w  = (const float*)d_in[5];
  const float* qa_b  = (const float*)d_in[6];
  const float* kv_w  = (const float*)d_in[7];
  const float* kv_b  = (const float*)d_in[8];
  const float* ka_w  = (const float*)d_in[9];
  const float* ka_b  = (const float*)d_in[10];
  const float* cc_w  = (const float*)d_in[11];
  const float* cc_b  = (const float*)d_in[12];
  const float* w5_w  = (const float*)d_in[13];
  const float* w5_b  = (const float*)d_in[14];
  const float* w6_w  = (const float*)d_in[15];
  const float* w6_b  = (const float*)d_in[16];
  const float* w7_w  = (const float*)d_in[17];
  const float* w7_b  = (const float*)d_in[18];
  const float* w8_w  = (const float*)d_in[19];
  const float* w8_b  = (const float*)d_in[20];
  const float* bil_w = (const float*)d_in[21];
  const float* t_o   = (const float*)d_in[22];
  float* out = (float*)d_out;

  char* ws = (char*)d_ws;
  ushortT* act16  = (ushortT*)(ws + OFF_ACT16);
  ushortT* actT16 = (ushortT*)(ws + OFF_ACTT16);
  ushortT* w16t   = (ushortT*)(ws + OFF_W16T);
  ushortT* proj16 = (ushortT*)(ws + OFF_PROJ16);
  ushortT* P16    = (ushortT*)(ws + OFF_P16);
  ushortT* vc16   = (ushortT*)(ws + OFF_VC16);
  ushortT* ac16   = (ushortT*)(ws + OFF_AC16);
  float*   pvv32  = (float*)(ws + OFF_PVV32);
  float*   pva32  = (float*)(ws + OFF_PVA32);
  ushortT* part   = (ushortT*)(ws + OFF_PART);
  ushortT* bil16  = (ushortT*)(ws + OFF_BIL16);
  ushortT* cfv16  = (ushortT*)(ws + OFF_CFV16);
  ushortT* cfa16  = (ushortT*)(ws + OFF_CFA16);

  k_cvt_acts<<<384, 256, 0, stream>>>(img, aud, com, act16);
  k_cvt_bil<<<2048, 256, 0, stream>>>(bil_w, bil16);
  k_transpose<<<528, 256, 0, stream>>>(img, aud, com, qv_w, qa_w, kv_w, ka_w, cc_w,
                                       w5_w, w6_w, w7_w, w8_w, actT16, w16t);
  k_linear5<<<320, 512, 0, stream>>>(act16, w16t, qv_b, qa_b, kv_b, ka_b, cc_b, proj16);
  k_attn<<<256, 512, 0, stream>>>(proj16, P16);
  k_pv<<<256, 512, 0, stream>>>(P16, actT16, pvv32, pva32, vc16, ac16);
  k_lin4c<<<128, 512, 0, stream>>>(vc16, ac16, w16t, w5_b, w6_b, w7_b, w8_b,
                                   pvv32, pva32, cfv16, cfa16);
  k_bilinear8<<<256, 512, 0, stream>>>(cfa16, cfv16, bil16, part);
  k_final2<<<512, 256, 0, stream>>>(part, img, aud, t_o, out, out + 524288);
}

// Round 9
// 136.731 us; speedup vs baseline: 3.2352x; 1.0854x over previous
//
#include <hip/hip_runtime.h>
#include <hip/hip_bf16.h>

// ---------- types ----------
typedef unsigned short ushortT;
typedef __bf16 bf16x8 __attribute__((ext_vector_type(8)));
typedef float f32x4 __attribute__((ext_vector_type(4)));
typedef ushortT ush8 __attribute__((ext_vector_type(8)));
typedef ushortT ush4 __attribute__((ext_vector_type(4)));

#define MFMA16(a, b, c) __builtin_amdgcn_mfma_f32_16x16x32_bf16((a), (b), (c), 0, 0, 0)

__device__ __forceinline__ ushortT f2b(float f) {
  __hip_bfloat16 h = __float2bfloat16(f);
  return __builtin_bit_cast(ushortT, h);
}
__device__ __forceinline__ float b2f(ushortT u) {
  __hip_bfloat16 h = __builtin_bit_cast(__hip_bfloat16, u);
  return __bfloat162float(h);
}

// async global->LDS, 16B per lane
__device__ __forceinline__ void async16(const void* g, void* l) {
  __builtin_amdgcn_global_load_lds((const __attribute__((address_space(1))) unsigned int*)g,
                                   (__attribute__((address_space(3))) unsigned int*)l, 16, 0, 0);
}

// scale 8 bf16 by scalar s in f32, round back to bf16 (v_cvt_pk_bf16_f32)
__device__ __forceinline__ bf16x8 scale8(bf16x8 a, float s) {
  union { bf16x8 v; unsigned int u[4]; } in, out;
  in.v = a;
#pragma unroll
  for (int p = 0; p < 4; p++) {
    float lo = __builtin_bit_cast(float, in.u[p] << 16);
    float hi = __builtin_bit_cast(float, in.u[p] & 0xffff0000u);
    lo *= s;
    hi *= s;
    unsigned int r;
    asm("v_cvt_pk_bf16_f32 %0, %1, %2" : "=v"(r) : "v"(lo), "v"(hi));
    out.u[p] = r;
  }
  return out.v;
}

// ---------- problem dims ----------
// B=4, S=512, D=256, ROWS = B*S = 2048
#define ACT_E 524288   // 2048*256 elements
#define WD_E  65536    // 256*256

// ---------- ws layout (bytes) ----------
#define OFF_ACT16   0u          // 3 * ACT_E * 2 = 3145728
#define OFF_ACTT16  3145728u
#define OFF_W16T    6291456u
#define OFF_PROJ16  7471104u
#define OFF_P16     12713984u   // (unused now, kept for layout stability)
#define OFF_VC16    21102592u
#define OFF_AC16    22151168u
#define OFF_PVV32   23199744u
#define OFF_PVA32   25296896u   // ends 27394048
#define OFF_PART    0u          // bf16: 32 * 524288 * 2 = 33554432 (overlaps dead transients)
#define OFF_BIL16   33554432u   // ends 67108864
#define OFF_CFV16   67108864u   // ACT_E*2
#define OFF_CFA16   68157440u   // ends 69206016

// =====================================================================
// 1) prep: acts cvt+transpose, weight transpose, bil cvt — one launch.
// grid 2576 x 256: bx<384 act tiles; 384..527 weight tiles; 528.. bil cvt.
__global__ void k_prep(const float* __restrict__ img, const float* __restrict__ aud,
                       const float* __restrict__ com,
                       const float* w0, const float* w1, const float* w2,
                       const float* w3, const float* w4, const float* w5,
                       const float* w6, const float* w7, const float* w8,
                       const float* __restrict__ bil,
                       ushortT* __restrict__ act16, ushortT* __restrict__ actT,
                       ushortT* __restrict__ wT, ushortT* __restrict__ bil16) {
  int tid = threadIdx.x;
  int bx = blockIdx.x;
  if (bx >= 528) {
    // bil cvt: 2048 blocks
    int i4 = (bx - 528) * 256 + tid;
#pragma unroll
    for (int q = 0; q < 8; q++) {
      int idx4 = i4 + q * 524288;
      float4 v = *(const float4*)(bil + (size_t)idx4 * 4);
      ush4 u = { f2b(v.x), f2b(v.y), f2b(v.z), f2b(v.w) };
      *(ush4*)(bil16 + (size_t)idx4 * 4) = u;
    }
    return;
  }
  __shared__ ushortT tl[64][72];
  const float* src;
  ushortT* dst;
  ushortT* lin = nullptr;
  int C, r0, c0, R;
  if (bx < 384) {
    int inst = bx >> 5, tile = bx & 31;
    int act = inst >> 2, bb = inst & 3;
    src = (act == 0 ? img : (act == 1 ? aud : com)) + bb * 131072;
    dst = actT + act * 524288 + bb * 131072;
    lin = act16 + act * 524288 + bb * 131072;
    R = 512; C = 256;
    r0 = (tile >> 2) * 64; c0 = (tile & 3) * 64;
  } else {
    int bw = bx - 384;
    int w = bw >> 4, tile = bw & 15;
    const float* s;
    switch (w) {
      case 0: s = w0; break; case 1: s = w1; break; case 2: s = w2; break;
      case 3: s = w3; break; case 4: s = w4; break; case 5: s = w5; break;
      case 6: s = w6; break; case 7: s = w7; break; default: s = w8; break;
    }
    src = s;
    dst = wT + w * 65536;
    R = 256; C = 256;
    r0 = (tile >> 2) * 64; c0 = (tile & 3) * 64;
  }
#pragma unroll
  for (int q = 0; q < 4; q++) {
    int rr = q * 16 + (tid >> 4);
    int cs = (tid & 15) * 4;
    float4 v = *(const float4*)(src + (r0 + rr) * C + c0 + cs);
    ush4 u = { f2b(v.x), f2b(v.y), f2b(v.z), f2b(v.w) };
    tl[rr][cs + 0] = u[0];
    tl[rr][cs + 1] = u[1];
    tl[rr][cs + 2] = u[2];
    tl[rr][cs + 3] = u[3];
    if (lin) *(ush4*)(lin + (r0 + rr) * 256 + c0 + cs) = u;   // linear bf16 copy
  }
  __syncthreads();
#pragma unroll
  for (int q = 0; q < 4; q++) {
    int cc = q * 16 + (tid >> 4);
    int rs = (tid & 15) * 4;
    ush4 u = { tl[rs + 0][cc], tl[rs + 1][cc], tl[rs + 2][cc], tl[rs + 3][cc] };
    *(ush4*)(dst + (c0 + cc) * R + r0 + rs) = u;
  }
}

// =====================================================================
// 2) five input linears
__global__ __launch_bounds__(512) void k_linear5(
    const ushortT* __restrict__ act16, const ushortT* __restrict__ wT,
    const float* __restrict__ b0, const float* __restrict__ b1,
    const float* __restrict__ b2, const float* __restrict__ b3,
    const float* __restrict__ b4, ushortT* __restrict__ proj16) {
  __shared__ ushortT Al[4][32][8];
  __shared__ ushortT Bl[4][256][8];
  const int tid = threadIdx.x, l = tid & 63, w = tid >> 6;
  const int bx = blockIdx.x;
  const int op = bx >> 6, sblk = bx & 63;
  const int s0 = sblk * 32;
  const int xsel = (op == 4) ? 2 : (op & 1);
  const ushortT* X = act16 + xsel * ACT_E;
  const ushortT* W = wT + op * WD_E;
  const float* bias = op == 0 ? b0 : op == 1 ? b1 : op == 2 ? b2 : op == 3 ? b3 : b4;
  ushortT* out = proj16 + op * ACT_E;

  f32x4 acc[2][2] = {};
  ush8 ra, rb[2];
  int a_row = tid >> 2, a_seg = tid & 3;

  auto sload = [&](int k0) {
    if (tid < 128) ra = *(const ush8*)(X + (s0 + a_row) * 256 + k0 + a_seg * 8);
#pragma unroll
    for (int q = 0; q < 2; q++) {
      int slot = tid + q * 512;
      rb[q] = *(const ush8*)(W + (slot >> 2) * 256 + k0 + (slot & 3) * 8);
    }
  };
  auto swrite = [&]() {
    if (tid < 128) *(ush8*)(&Al[a_seg][a_row][0]) = ra;
#pragma unroll
    for (int q = 0; q < 2; q++) {
      int slot = tid + q * 512;
      *(ush8*)(&Bl[slot & 3][slot >> 2][0]) = rb[q];
    }
  };

  sload(0); swrite(); __syncthreads();
  for (int s = 0; s < 8; s++) {
    if (s < 7) sload((s + 1) * 32);
    int ks = l >> 4;
    bf16x8 a[2], bb[2];
#pragma unroll
    for (int m = 0; m < 2; m++) a[m] = *(const bf16x8*)(&Al[ks][m * 16 + (l & 15)][0]);
#pragma unroll
    for (int n = 0; n < 2; n++) bb[n] = *(const bf16x8*)(&Bl[ks][w * 32 + n * 16 + (l & 15)][0]);
#pragma unroll
    for (int m = 0; m < 2; m++)
#pragma unroll
      for (int n = 0; n < 2; n++) acc[m][n] = MFMA16(a[m], bb[n], acc[m][n]);
    if (s == 7) break;
    __syncthreads();
    swrite();
    __syncthreads();
  }
#pragma unroll
  for (int m = 0; m < 2; m++)
#pragma unroll
    for (int n = 0; n < 2; n++)
#pragma unroll
      for (int r = 0; r < 4; r++) {
        int row = s0 + m * 16 + (l >> 4) * 4 + r;
        int col = w * 32 + n * 16 + (l & 15);
        out[row * 256 + col] = f2b(acc[m][n][r] + bias[col]);
      }
}

// =====================================================================
// 3) fused attention + PV: P = softmax(QK^T)/16 stays in LDS; then P@V.
// grid 256 x 512 : p=bx>>6, b=(bx>>4)&3, sblk=bx&15 (32 q-rows per block).
// Kills the 8.4MB P16 HBM round-trip + one launch.
__global__ __launch_bounds__(512) void k_attnpv(
    const ushortT* __restrict__ proj16, const ushortT* __restrict__ actT,
    float* __restrict__ pvv, float* __restrict__ pva,
    ushortT* __restrict__ vc16, ushortT* __restrict__ ac16) {
  // arena: Ql @0 16KB (phase 3: Vl aliases); Kl @16384 32KB; Pl @49152 32KB;
  // red @81920 1KB.  total 82944.
  __shared__ char arena[82944];
  auto Ql = (ushortT(*)[4][32][8])(arena);          // [8][4][32][8]
  auto Kl = (ushortT(*)[512][8])(arena + 16384);    // [4][512][8]
  auto Pl = (ushortT(*)[4][32][8])(arena + 49152);  // [16][4][32][8]
  auto Vl = (ushortT(*)[256][8])(arena);            // [4][256][8] (aliases Ql)
  auto red = (float(*)[8])(arena + 81920);          // [32][8]

  const int tid = threadIdx.x, l = tid & 63, w = tid >> 6;
  const int bx = blockIdx.x;
  const int p = bx >> 6, b = (bx >> 4) & 3, sblk = bx & 15;
  const int s0 = sblk * 32;
  const int qsel = (p < 2) ? 0 : 1;
  const int ksel = (p == 0) ? 2 : (p == 2) ? 3 : 4;
  const int vsel = (p == 0) ? 0 : (p == 2) ? 1 : 2;
  const ushortT* Q = proj16 + qsel * ACT_E + b * 131072;
  const ushortT* K = proj16 + ksel * ACT_E + b * 131072;
  const ushortT* VT = actT + vsel * ACT_E + b * 131072;   // [256 d][512 t]

  // ---- phase 1: stage Q (32x256) ----
#pragma unroll
  for (int q = 0; q < 2; q++) {
    int slot = tid + q * 512;
    int row = slot >> 5, seg = slot & 31;
    ush8 v = *(const ush8*)(Q + (s0 + row) * 256 + seg * 8);
    *(ush8*)(&Ql[seg >> 2][seg & 3][row][0]) = v;
  }

  f32x4 acc[2][4] = {};
  ush8 rk[4];
  auto kload = [&](int d0) {
#pragma unroll
    for (int q = 0; q < 4; q++) {
      int slot = tid + q * 512;
      rk[q] = *(const ush8*)(K + (slot >> 2) * 256 + d0 + (slot & 3) * 8);
    }
  };
  auto kwrite = [&]() {
#pragma unroll
    for (int q = 0; q < 4; q++) {
      int slot = tid + q * 512;
      *(ush8*)(&Kl[slot & 3][slot >> 2][0]) = rk[q];
    }
  };

  kload(0); kwrite(); __syncthreads();
  for (int s = 0; s < 8; s++) {
    if (s < 7) kload((s + 1) * 32);
    int ks = l >> 4;
    bf16x8 a[2], bb[4];
#pragma unroll
    for (int m = 0; m < 2; m++) a[m] = *(const bf16x8*)(&Ql[s][ks][m * 16 + (l & 15)][0]);
#pragma unroll
    for (int n = 0; n < 4; n++) bb[n] = *(const bf16x8*)(&Kl[ks][w * 64 + n * 16 + (l & 15)][0]);
#pragma unroll
    for (int m = 0; m < 2; m++)
#pragma unroll
      for (int n = 0; n < 4; n++) acc[m][n] = MFMA16(a[m], bb[n], acc[m][n]);
    if (s == 7) break;
    __syncthreads();
    kwrite();
    __syncthreads();
  }

  // ---- phase 2: softmax over t (512), write P (bf16) into Pl ----
  float gmax[2][4];
#pragma unroll
  for (int m = 0; m < 2; m++)
#pragma unroll
    for (int r = 0; r < 4; r++) {
      float v = fmaxf(fmaxf(acc[m][0][r], acc[m][1][r]), fmaxf(acc[m][2][r], acc[m][3][r]));
#pragma unroll
      for (int off = 1; off < 16; off <<= 1) v = fmaxf(v, __shfl_xor(v, off, 16));
      if ((l & 15) == 0) red[m * 16 + (l >> 4) * 4 + r][w] = v;
    }
  __syncthreads();
#pragma unroll
  for (int m = 0; m < 2; m++)
#pragma unroll
    for (int r = 0; r < 4; r++) {
      int sr = m * 16 + (l >> 4) * 4 + r;
      float g = red[sr][0];
#pragma unroll
      for (int ww = 1; ww < 8; ww++) g = fmaxf(g, red[sr][ww]);
      gmax[m][r] = g;
    }
  __syncthreads();
#pragma unroll
  for (int m = 0; m < 2; m++)
#pragma unroll
    for (int r = 0; r < 4; r++) {
      float ssum = 0.f;
#pragma unroll
      for (int n = 0; n < 4; n++) {
        float e = __expf(acc[m][n][r] - gmax[m][r]);
        acc[m][n][r] = e;
        ssum += e;
      }
#pragma unroll
      for (int off = 1; off < 16; off <<= 1) ssum += __shfl_xor(ssum, off, 16);
      if ((l & 15) == 0) red[m * 16 + (l >> 4) * 4 + r][w] = ssum;
    }
  __syncthreads();
#pragma unroll
  for (int m = 0; m < 2; m++)
#pragma unroll
    for (int r = 0; r < 4; r++) {
      int sr = m * 16 + (l >> 4) * 4 + r;
      float tot = 0.f;
#pragma unroll
      for (int ww = 0; ww < 8; ww++) tot += red[sr][ww];
      float sc = 0.0625f / tot;
#pragma unroll
      for (int n = 0; n < 4; n++) {
        // col c = w*64 + n*16 + (l&15): Pl[c>>5][(c>>3)&3][sr][c&7]
        int S = w * 2 + (n >> 1);
        int KS = ((n & 1) << 1) | ((l & 15) >> 3);
        Pl[S][KS][sr][l & 7] = f2b(acc[m][n][r] * sc);
      }
    }

  // ---- phase 3: out = P @ V^T-staged (BM=32, N=256, K=512) ----
  f32x4 acc2[2][2] = {};
  ush8 rv[2];
  auto vload = [&](int t0) {
#pragma unroll
    for (int q = 0; q < 2; q++) {
      int slot = tid + q * 512;
      rv[q] = *(const ush8*)(VT + (slot >> 2) * 512 + t0 + (slot & 3) * 8);
    }
  };
  auto vwrite = [&]() {
#pragma unroll
    for (int q = 0; q < 2; q++) {
      int slot = tid + q * 512;
      *(ush8*)(&Vl[slot & 3][slot >> 2][0]) = rv[q];
    }
  };

  vload(0);
  __syncthreads();      // Pl visible; all Ql reads (phase 1) long done -> Vl safe
  vwrite();
  __syncthreads();
  for (int s = 0; s < 16; s++) {
    if (s < 15) vload((s + 1) * 32);
    int ks = l >> 4;
    bf16x8 a[2], bb[2];
#pragma unroll
    for (int m = 0; m < 2; m++) a[m] = *(const bf16x8*)(&Pl[s][ks][m * 16 + (l & 15)][0]);
#pragma unroll
    for (int n = 0; n < 2; n++) bb[n] = *(const bf16x8*)(&Vl[ks][w * 32 + n * 16 + (l & 15)][0]);
#pragma unroll
    for (int m = 0; m < 2; m++)
#pragma unroll
      for (int n = 0; n < 2; n++) acc2[m][n] = MFMA16(a[m], bb[n], acc2[m][n]);
    if (s == 15) break;
    __syncthreads();
    vwrite();
    __syncthreads();
  }
#pragma unroll
  for (int m = 0; m < 2; m++)
#pragma unroll
    for (int n = 0; n < 2; n++)
#pragma unroll
      for (int r = 0; r < 4; r++) {
        int row = s0 + m * 16 + (l >> 4) * 4 + r;
        int col = w * 32 + n * 16 + (l & 15);
        int gi = (b * 512 + row) * 256 + col;
        float v = acc2[m][n][r];
        if (p == 0) pvv[gi] = v;
        else if (p == 1) vc16[gi] = f2b(v);
        else if (p == 2) pva[gi] = v;
        else ac16[gi] = f2b(v);
      }
}

// =====================================================================
// 4) two linears + combine
__global__ __launch_bounds__(512) void k_lin4c(
    const ushortT* __restrict__ vc16, const ushortT* __restrict__ ac16,
    const ushortT* __restrict__ wT,
    const float* __restrict__ w5b, const float* __restrict__ w6b,
    const float* __restrict__ w7b, const float* __restrict__ w8b,
    const float* __restrict__ pvv, const float* __restrict__ pva,
    ushortT* __restrict__ cfv, ushortT* __restrict__ cfa) {
  __shared__ ushortT Al[4][32][8];
  __shared__ ushortT B1[4][256][8];
  __shared__ ushortT B2[4][256][8];
  const int tid = threadIdx.x, l = tid & 63, w = tid >> 6;
  const int bx = blockIdx.x;
  const int side = bx >> 6, sblk = bx & 63;
  const int s0 = sblk * 32;
  const ushortT* A = side ? ac16 : vc16;
  const ushortT* W1 = wT + (side ? 7 : 5) * WD_E;
  const ushortT* W2 = wT + (side ? 8 : 6) * WD_E;
  const float* bb1 = side ? w7b : w5b;
  const float* bb2 = side ? w8b : w6b;
  const float* pv = side ? pva : pvv;
  ushortT* out = side ? cfa : cfv;

  f32x4 acc1[2][2] = {}, acc2[2][2] = {};
  ush8 ra, rb1[2], rb2[2];
  int a_row = tid >> 2, a_seg = tid & 3;
  auto sload = [&](int k0) {
    if (tid < 128) ra = *(const ush8*)(A + (s0 + a_row) * 256 + k0 + a_seg * 8);
#pragma unroll
    for (int q = 0; q < 2; q++) {
      int slot = tid + q * 512;
      rb1[q] = *(const ush8*)(W1 + (slot >> 2) * 256 + k0 + (slot & 3) * 8);
      rb2[q] = *(const ush8*)(W2 + (slot >> 2) * 256 + k0 + (slot & 3) * 8);
    }
  };
  auto swrite = [&]() {
    if (tid < 128) *(ush8*)(&Al[a_seg][a_row][0]) = ra;
#pragma unroll
    for (int q = 0; q < 2; q++) {
      int slot = tid + q * 512;
      *(ush8*)(&B1[slot & 3][slot >> 2][0]) = rb1[q];
      *(ush8*)(&B2[slot & 3][slot >> 2][0]) = rb2[q];
    }
  };

  sload(0); swrite(); __syncthreads();
  for (int s = 0; s < 8; s++) {
    if (s < 7) sload((s + 1) * 32);
    int ks = l >> 4;
    bf16x8 a[2], x1[2], x2[2];
#pragma unroll
    for (int m = 0; m < 2; m++) a[m] = *(const bf16x8*)(&Al[ks][m * 16 + (l & 15)][0]);
#pragma unroll
    for (int n = 0; n < 2; n++) {
      x1[n] = *(const bf16x8*)(&B1[ks][w * 32 + n * 16 + (l & 15)][0]);
      x2[n] = *(const bf16x8*)(&B2[ks][w * 32 + n * 16 + (l & 15)][0]);
    }
#pragma unroll
    for (int m = 0; m < 2; m++)
#pragma unroll
      for (int n = 0; n < 2; n++) {
        acc1[m][n] = MFMA16(a[m], x1[n], acc1[m][n]);
        acc2[m][n] = MFMA16(a[m], x2[n], acc2[m][n]);
      }
    if (s == 7) break;
    __syncthreads();
    swrite();
    __syncthreads();
  }
#pragma unroll
  for (int m = 0; m < 2; m++)
#pragma unroll
    for (int n = 0; n < 2; n++)
#pragma unroll
      for (int r = 0; r < 4; r++) {
        int row = s0 + m * 16 + (l >> 4) * 4 + r;
        int col = w * 32 + n * 16 + (l & 15);
        int gi = row * 256 + col;
        float u1 = acc1[m][n][r] + bb1[col];
        float u2 = acc2[m][n][r] + bb2[col];
        out[gi] = f2b((1.f + u1) * pv[gi] + u2);
      }
}

// =====================================================================
// 5) bilinear v8 (unchanged from R8): 64x128 wave tiles, spill-proof.
__global__ __launch_bounds__(512, 1) void k_bilinear8(
    const ushortT* __restrict__ cfa, const ushortT* __restrict__ cfv,
    const ushortT* __restrict__ W, ushortT* __restrict__ part) {
  __shared__ char arena[140288];
  const int tid = threadIdx.x, l = tid & 63, w = tid >> 6;
  const int d = blockIdx.x;
  const int L = (d & 7) * 32 + (d >> 3);
  const int ic = L >> 3;
  const int mb = L & 7;
  const int r0 = mb * 256;
  const int icb = ic * 8;
  const int wr = w >> 1, wc = w & 1;

  float* cfvl = (float*)(arena + 131072);
  if (tid < 256) {
    ush8 v = *(const ush8*)(cfv + (size_t)(r0 + tid) * 256 + icb);
    float* dp = cfvl + tid * 9;
#pragma unroll
    for (int q = 0; q < 8; q++) dp[q] = b2f(v[q]);
  }

  int pS[4], aOff[4], bOff[4], cvIdx[4];
#pragma unroll
  for (int s = 0; s < 4; s++) {
    int p = (tid + s * 512) * 16;
    int lg = p ^ (((p >> 7) & 7) << 4);
    int row = lg >> 7, colb = lg & 127;
    pS[s] = p;
    cvIdx[s] = row * 9;
    aOff[s] = (r0 + row) * 512 + colb;
    bOff[s] = row * 131072 + icb * 512 + colb;
  }
  const char* cfaB = (const char*)cfa;
  const char* WB = (const char*)W;

  int aoff[2][4], boff[2][8];
#pragma unroll
  for (int m = 0; m < 4; m++) {
    int row = wr * 64 + m * 16 + (l & 15);
    int b0 = row * 128 + (l >> 4) * 16;
    int msk = (row & 7) << 4;
    aoff[0][m] = b0 ^ msk;
    aoff[1][m] = (b0 + 64) ^ msk;
  }
#pragma unroll
  for (int n = 0; n < 8; n++) {
    int row = wc * 128 + n * 16 + (l & 15);
    int b0 = row * 128 + (l >> 4) * 16;
    int msk = (row & 7) << 4;
    boff[0][n] = b0 ^ msk;
    boff[1][n] = (b0 + 64) ^ msk;
  }

  ush8 arg[4];
  auto loadA = [&](int t) {
    int ja = (t & 3) << 7;
#pragma unroll
    for (int s = 0; s < 4; s++) arg[s] = *(const ush8*)(cfaB + aOff[s] + ja);
  };
  auto gloadB = [&](int t, char* Bb) {
    int jb = ((t >> 2) << 9) + ((t & 3) << 7);
#pragma unroll
    for (int s = 0; s < 4; s++) async16(WB + bOff[s] + jb, Bb + pS[s]);
  };
  auto writeA = [&](int t, char* Ab) {
    int ii = t >> 2;
#pragma unroll
    for (int s = 0; s < 4; s++) {
      float sc = cfvl[cvIdx[s] + ii];
      *(bf16x8*)(Ab + pS[s]) = scale8(__builtin_bit_cast(bf16x8, arg[s]), sc);
    }
  };

  f32x4 macc[4][8] = {};

  loadA(0);
  gloadB(0, arena + 65536);
  __syncthreads();
  writeA(0, arena);
  __syncthreads();

  for (int t = 0; t < 32; t++) {
    char* Ab = arena + ((t & 1) << 15);
    char* Bb = arena + 65536 + ((t & 1) << 15);
    char* An = arena + (((t + 1) & 1) << 15);
    char* Bn = arena + 65536 + (((t + 1) & 1) << 15);

    bf16x8 a0[4];
#pragma unroll
    for (int m = 0; m < 4; m++) a0[m] = *(const bf16x8*)(Ab + aoff[0][m]);

    if (t < 31) { loadA(t + 1); gloadB(t + 1, Bn); }

    {
      bf16x8 bl[4];
#pragma unroll
      for (int n = 0; n < 4; n++) bl[n] = *(const bf16x8*)(Bb + boff[0][n]);
      __builtin_amdgcn_s_setprio(1);
#pragma unroll
      for (int m = 0; m < 4; m++)
#pragma unroll
        for (int n = 0; n < 4; n++) macc[m][n] = MFMA16(a0[m], bl[n], macc[m][n]);
      __builtin_amdgcn_s_setprio(0);
    }
    {
      bf16x8 bh[4];
#pragma unroll
      for (int n = 0; n < 4; n++) bh[n] = *(const bf16x8*)(Bb + boff[0][n + 4]);
      __builtin_amdgcn_s_setprio(1);
#pragma unroll
      for (int m = 0; m < 4; m++)
#pragma unroll
        for (int n = 0; n < 4; n++) macc[m][n + 4] = MFMA16(a0[m], bh[n], macc[m][n + 4]);
      __builtin_amdgcn_s_setprio(0);
    }

    if (t < 31) writeA(t + 1, An);

    bf16x8 a1[4];
#pragma unroll
    for (int m = 0; m < 4; m++) a1[m] = *(const bf16x8*)(Ab + aoff[1][m]);
    {
      bf16x8 bl[4];
#pragma unroll
      for (int n = 0; n < 4; n++) bl[n] = *(const bf16x8*)(Bb + boff[1][n]);
      __builtin_amdgcn_s_setprio(1);
#pragma unroll
      for (int m = 0; m < 4; m++)
#pragma unroll
        for (int n = 0; n < 4; n++) macc[m][n] = MFMA16(a1[m], bl[n], macc[m][n]);
      __builtin_amdgcn_s_setprio(0);
    }
    {
      bf16x8 bh[4];
#pragma unroll
      for (int n = 0; n < 4; n++) bh[n] = *(const bf16x8*)(Bb + boff[1][n + 4]);
      __builtin_amdgcn_s_setprio(1);
#pragma unroll
      for (int m = 0; m < 4; m++)
#pragma unroll
        for (int n = 0; n < 4; n++) macc[m][n + 4] = MFMA16(a1[m], bh[n], macc[m][n + 4]);
      __builtin_amdgcn_s_setprio(0);
    }

    __syncthreads();
  }

  ushortT* dst = part + (size_t)ic * 524288 + (size_t)r0 * 256;
#pragma unroll
  for (int m = 0; m < 4; m++)
#pragma unroll
    for (int n = 0; n < 8; n++)
#pragma unroll
      for (int r = 0; r < 4; r++)
        dst[(wr * 64 + m * 16 + ((l >> 4) << 2) + r) * 256 + wc * 128 + n * 16 + (l & 15)] =
            f2b(macc[m][n][r]);
}

// =====================================================================
// 6) final gate + partial reduction over 32 bf16 ic-chunks
__global__ void k_final2(const ushortT* __restrict__ part, const float* __restrict__ img,
                         const float* __restrict__ aud, const float* __restrict__ t_o,
                         float* __restrict__ out0, float* __restrict__ out1) {
  int i = blockIdx.x * 256 + threadIdx.x;
  float t = t_o[0];
  float4 m = {0.f, 0.f, 0.f, 0.f};
#pragma unroll
  for (int ic = 0; ic < 32; ic++) {
    ush4 p = *(const ush4*)(part + (size_t)ic * 524288 + (size_t)i * 4);
    m.x += b2f(p[0]); m.y += b2f(p[1]); m.z += b2f(p[2]); m.w += b2f(p[3]);
  }
  float4 a = ((const float4*)img)[i];
  float4 u = ((const float4*)aud)[i];
  float4 o0, o1;
  {
    float j = 1.f / (1.f + __expf(-m.x)); float Z = t * j * a.x + (1.f - j) * u.x;
    o0.x = Z + a.x; o1.x = Z + u.x;
  }
  {
    float j = 1.f / (1.f + __expf(-m.y)); float Z = t * j * a.y + (1.f - j) * u.y;
    o0.y = Z + a.y; o1.y = Z + u.y;
  }
  {
    float j = 1.f / (1.f + __expf(-m.z)); float Z = t * j * a.z + (1.f - j) * u.z;
    o0.z = Z + a.z; o1.z = Z + u.z;
  }
  {
    float j = 1.f / (1.f + __expf(-m.w)); float Z = t * j * a.w + (1.f - j) * u.w;
    o0.w = Z + a.w; o1.w = Z + u.w;
  }
  ((float4*)out0)[i] = o0;
  ((float4*)out1)[i] = o1;
}

// =====================================================================
extern "C" void kernel_launch(void* const* d_in, const int* in_sizes, int n_in,
                              void* d_out, int out_size, void* d_ws, size_t ws_size,
                              hipStream_t stream) {
  const float* img   = (const float*)d_in[0];
  const float* aud   = (const float*)d_in[1];
  const float* com   = (const float*)d_in[2];
  const float* qv_w  = (const float*)d_in[3];
  const float* qv_b  = (const float*)d_in[4];
  const float* qa_w  = (const float*)d_in[5];
  const float* qa_b  = (const float*)d_in[6];
  const float* kv_w  = (const float*)d_in[7];
  const float* kv_b  = (const float*)d_in[8];
  const float* ka_w  = (const float*)d_in[9];
  const float* ka_b  = (const float*)d_in[10];
  const float* cc_w  = (const float*)d_in[11];
  const float* cc_b  = (const float*)d_in[12];
  const float* w5_w  = (const float*)d_in[13];
  const float* w5_b  = (const float*)d_in[14];
  const float* w6_w  = (const float*)d_in[15];
  const float* w6_b  = (const float*)d_in[16];
  const float* w7_w  = (const float*)d_in[17];
  const float* w7_b  = (const float*)d_in[18];
  const float* w8_w  = (const float*)d_in[19];
  const float* w8_b  = (const float*)d_in[20];
  const float* bil_w = (const float*)d_in[21];
  const float* t_o   = (const float*)d_in[22];
  float* out = (float*)d_out;

  char* ws = (char*)d_ws;
  ushortT* act16  = (ushortT*)(ws + OFF_ACT16);
  ushortT* actT16 = (ushortT*)(ws + OFF_ACTT16);
  ushortT* w16t   = (ushortT*)(ws + OFF_W16T);
  ushortT* proj16 = (ushortT*)(ws + OFF_PROJ16);
  ushortT* vc16   = (ushortT*)(ws + OFF_VC16);
  ushortT* ac16   = (ushortT*)(ws + OFF_AC16);
  float*   pvv32  = (float*)(ws + OFF_PVV32);
  float*   pva32  = (float*)(ws + OFF_PVA32);
  ushortT* part   = (ushortT*)(ws + OFF_PART);
  ushortT* bil16  = (ushortT*)(ws + OFF_BIL16);
  ushortT* cfv16  = (ushortT*)(ws + OFF_CFV16);
  ushortT* cfa16  = (ushortT*)(ws + OFF_CFA16);

  k_prep<<<2576, 256, 0, stream>>>(img, aud, com, qv_w, qa_w, kv_w, ka_w, cc_w,
                                   w5_w, w6_w, w7_w, w8_w, bil_w,
                                   act16, actT16, w16t, bil16);
  k_linear5<<<320, 512, 0, stream>>>(act16, w16t, qv_b, qa_b, kv_b, ka_b, cc_b, proj16);
  k_attnpv<<<256, 512, 0, stream>>>(proj16, actT16, pvv32, pva32, vc16, ac16);
  k_lin4c<<<128, 512, 0, stream>>>(vc16, ac16, w16t, w5_b, w6_b, w7_b, w8_b,
                                   pvv32, pva32, cfv16, cfa16);
  k_bilinear8<<<256, 512, 0, stream>>>(cfa16, cfv16, bil16, part);
  k_final2<<<512, 256, 0, stream>>>(part, img, aud, t_o, out, out + 524288);
}